// Round 10
// baseline (996.233 us; speedup 1.0000x reference)
//
#include <hip/hip_runtime.h>
#include <hip/hip_cooperative_groups.h>

namespace cg = cooperative_groups;

#define CDIV(a,b) (((a)+(b)-1)/(b))
#define CHUNK 4096

// Combined node ids: mol [0,Nm), prot [Nm,Nm+Np).  Bucket = node >> 12 (4096 nodes/bkt,
// NBKT <= 64; node ids < 2^18 so (dlo<<18)|src packs an edge into one int).
// Single cooperative kernel runs: zero-init -> u/v+flag -> bucket counts -> bin (dynamic
// reservation, packed, coalesced) -> accA(deg) -> xi -> accB(s_acc) -> si -> accC(PM,
// fast only) -> rank-2 pooled output (fast only), with grid.sync() between phases.
// Fallback (b1 != 0): CSR pipeline in guarded separate kernels (no-ops on fast path).

__global__ __launch_bounds__(256) void k_mega(
        const float* __restrict__ mol_x, const int* __restrict__ me,
        const float* __restrict__ prot_x, const int* __restrict__ pe,
        const float* __restrict__ W1, const float* __restrict__ b1,
        const float* __restrict__ W2, const float* __restrict__ b2,
        int Nm, int Em, int Np, int Ep,
        int* __restrict__ hist, float* __restrict__ s_acc,
        float* __restrict__ PM, float* __restrict__ pool,
        int* __restrict__ btot, int* __restrict__ gcur, int* __restrict__ pkb,
        float* __restrict__ xi, float2* __restrict__ si,
        float* __restrict__ u, float* __restrict__ v, int* __restrict__ flags) {
    cg::grid_group grid = cg::this_grid();
    __shared__ __align__(16) char sbig[32768];       // union: lpk+lbkt / h / acc / pm / sA,sB
    __shared__ int bbp[64], cnt[64], cst[64], cur[64], wbase[64];
    __shared__ int nz;

    const int t    = threadIdx.x;
    const int bid  = blockIdx.x;
    const int nblk = gridDim.x;
    const int Ntot = Nm + Np;
    const int Etot = Em + Ep;
    const int NBKT = (Ntot + 4095) >> 12;
    const int nchunk = CDIV(Etot, CHUNK);
    const int gtid = bid * 256 + t;
    const int gstr = nblk * 256;

    // ---- P0: zero accumulators; block 0 computes u,v and the b1!=0 flag ----
    for (int i = gtid; i < Ntot; i += gstr) { hist[i] = 0; s_acc[i] = 0.f; }
    for (int i = gtid; i < 2 * Ntot; i += gstr) PM[i] = 0.f;
    if (gtid < 256) pool[gtid] = 0.f;
    if (gtid < 64) { btot[gtid] = 0; gcur[gtid] = 0; }
    if (bid == 0) {
        if (t == 0) nz = 0;
        __syncthreads();
        if (t < 128) {
            if (b1[t] != 0.f) atomicOr(&nz, 1);
            float au = 0.f, av = 0.f;
            for (int j = 0; j < 128; ++j) {
                float w = W1[j], w2 = W2[j * 128 + t];
                au = fmaf(fmaxf(w, 0.f), w2, au);
                av = fmaf(fmaxf(-w, 0.f), w2, av);
            }
            u[t] = au; v[t] = av;
        }
        __syncthreads();
        if (t == 0) flags[0] = nz;
    }
    grid.sync();

    // ---- P1: per-bucket edge totals ----
    for (int c = bid; c < nchunk; c += nblk) {
        int e0 = c * CHUNK, e1 = min(e0 + CHUNK, Etot);
        if (t < 64) cnt[t] = 0;
        __syncthreads();
        for (int e = e0 + t; e < e1; e += 256) {
            int d = (e < Em) ? me[Em + e] : (pe[Ep + (e - Em)] + Nm);
            atomicAdd(&cnt[d >> 12], 1);
        }
        __syncthreads();
        if (t < NBKT && cnt[t]) atomicAdd(&btot[t], cnt[t]);
        __syncthreads();
    }
    grid.sync();

    // ---- P2: bin edges (dynamic reservation, packed, coalesced writeout) ----
    {
        int* lpk = (int*)sbig;                               // 16 KB
        unsigned char* lbkt = (unsigned char*)(sbig + 16384); // 4 KB
        if (t == 0) {
            int run = 0;
            for (int b = 0; b < NBKT; ++b) { bbp[b] = run; run += btot[b]; }
        }
        __syncthreads();
        for (int c = bid; c < nchunk; c += nblk) {
            int e0 = c * CHUNK, e1 = min(e0 + CHUNK, Etot);
            int ne = e1 - e0;
            if (t < 64) cnt[t] = 0;
            __syncthreads();
            for (int e = e0 + t; e < e1; e += 256) {
                int d = (e < Em) ? me[Em + e] : (pe[Ep + (e - Em)] + Nm);
                atomicAdd(&cnt[d >> 12], 1);
            }
            __syncthreads();
            if (t == 0) {
                int run = 0;
                for (int b = 0; b < NBKT; ++b) { cst[b] = run; cur[b] = run; run += cnt[b]; }
            }
            __syncthreads();
            if (t < NBKT) wbase[t] = bbp[t] + (cnt[t] ? atomicAdd(&gcur[t], cnt[t]) : 0);
            __syncthreads();
            for (int e = e0 + t; e < e1; e += 256) {
                int s, d;
                if (e < Em) { s = me[e];            d = me[Em + e]; }
                else        { int ee = e - Em; s = pe[ee] + Nm; d = pe[Ep + ee] + Nm; }
                int b = d >> 12;
                int p = atomicAdd(&cur[b], 1);
                lpk[p]  = ((d & 4095) << 18) | s;            // node ids < 2^18
                lbkt[p] = (unsigned char)b;
            }
            __syncthreads();
            for (int i = t; i < ne; i += 256) {
                int b = lbkt[i];
                pkb[wbase[b] + (i - cst[b])] = lpk[i];
            }
            __syncthreads();
        }
    }
    grid.sync();

    // ---- P3: accA — degree histogram (bbp persists in LDS) ----
    {
        int WPB = min(max(nblk / NBKT, 1), 32);
        int* h = (int*)sbig;                                 // 16 KB
        int b = bid / WPB, sl = bid % WPB;
        if (b < NBKT) {
            int bs = bbp[b];
            int be = (b + 1 < NBKT) ? bbp[b + 1] : Etot;
            for (int k = t; k < 4096; k += 256) h[k] = 0;
            __syncthreads();
            for (int i = bs + sl * 256 + t; i < be; i += WPB * 256)
                atomicAdd(&h[pkb[i] >> 18], 1);
            __syncthreads();
            for (int k = t; k < 4096; k += 256) {
                int vv = h[k];
                int node = (b << 12) + k;
                if (vv && node < Ntot) atomicAdd(&hist[node], vv);
            }
        }
    }
    grid.sync();

    // ---- P4: xi = x * rsqrt(deg+1) ----
    for (int i = gtid; i < Ntot; i += gstr) {
        float x = (i < Nm) ? mol_x[i] : prot_x[i - Nm];
        xi[i] = x * rsqrtf((float)(hist[i] + 1));
    }
    grid.sync();

    // ---- P5: accB — s_acc[d] += xi[src] ----
    {
        int WPB = min(max(nblk / NBKT, 1), 32);
        float* acc = (float*)sbig;                           // 16 KB
        int b = bid / WPB, sl = bid % WPB;
        if (b < NBKT) {
            int bs = bbp[b];
            int be = (b + 1 < NBKT) ? bbp[b + 1] : Etot;
            for (int k = t; k < 4096; k += 256) acc[k] = 0.f;
            __syncthreads();
            for (int i = bs + sl * 256 + t; i < be; i += WPB * 256) {
                int pk = pkb[i];
                atomicAdd(&acc[pk >> 18], xi[pk & 0x3FFFF]);
            }
            __syncthreads();
            for (int k = t; k < 4096; k += 256) {
                float vv = acc[k];
                int node = (b << 12) + k;
                if (vv != 0.f && node < Ntot) atomicAdd(&s_acc[node], vv);
            }
        }
    }
    grid.sync();

    // ---- P6: si = (inv*(s_acc+xi), inv) ----
    for (int i = gtid; i < Ntot; i += gstr) {
        float iv = rsqrtf((float)(hist[i] + 1));
        si[i] = make_float2(iv * (s_acc[i] + xi[i]), iv);
    }
    grid.sync();

    int flagv = *(volatile int*)flags;

    // ---- P7: accC — P/M sign-split sums (fast path only) ----
    if (!flagv) {
        int WPB = min(max(nblk / (NBKT * 2), 1), 16);
        float* pm = (float*)sbig;                            // 32 KB
        int b = bid / WPB, sl = bid % WPB;
        if (b < NBKT) {
            int bs = bbp[b];
            int be = (b + 1 < NBKT) ? bbp[b + 1] : Etot;
            for (int k = t; k < 8192; k += 256) pm[k] = 0.f;
            __syncthreads();
            for (int i = bs + sl * 256 + t; i < be; i += WPB * 256) {
                int pk = pkb[i];
                float2 q = si[pk & 0x3FFFF];
                float val = q.y * q.x;
                int lo = (pk >> 18) * 2;
                if (val > 0.f)      atomicAdd(&pm[lo],     val);
                else if (val < 0.f) atomicAdd(&pm[lo + 1], -val);
            }
            __syncthreads();
            for (int k = t; k < 8192; k += 256) {
                float vv = pm[k];
                int node = (b << 12) + (k >> 1);
                if (vv != 0.f && node < Ntot) atomicAdd(&PM[2 * node + (k & 1)], vv);
            }
        }
    }
    grid.sync();

    // ---- P8: rank-2 pooled output, tile-transposed (fast path only) ----
    if (!flagv) {
        float* sAf = (float*)sbig;
        float* sBf = sAf + 256;
        int k = t & 127, grp = t >> 7;
        float uk = u[k], vk = v[k], bk = b2[k];
        float accM = 0.f, accP = 0.f;
        int ntm = CDIV(Nm, 128), ntp = CDIV(Np, 128), ntt = ntm + ntp;
        for (int tb = bid * 2; tb < ntt; tb += nblk * 2) {
            int tile = tb + grp;
            int d0 = 0, nn = 0;
            bool isM = true;
            if (tile < ntt) {
                if (tile < ntm) { d0 = tile * 128; nn = min(128, Nm - d0); }
                else { isM = false; d0 = Nm + (tile - ntm) * 128; nn = min(128, Ntot - d0); }
            }
            float A = 0.f, B = 0.f;
            if (k < nn) {
                float2 q   = si[d0 + k];                      // coalesced
                float2 pm2 = *(const float2*)&PM[2 * (d0 + k)];
                float iv = q.y;
                A = iv * fmaf(iv, fmaxf(q.x, 0.f), pm2.x);
                B = iv * fmaf(iv, fmaxf(-q.x, 0.f), pm2.y);
            }
            __syncthreads();
            sAf[grp * 128 + k] = A;
            sBf[grp * 128 + k] = B;
            __syncthreads();
            float lacc = 0.f;
            #pragma unroll 8
            for (int i = 0; i < nn; ++i)
                lacc += fmaxf(fmaf(sAf[grp * 128 + i], uk,
                                   fmaf(sBf[grp * 128 + i], vk, bk)), 0.f);
            if (isM) accM += lacc; else accP += lacc;
        }
        __syncthreads();
        sAf[t] = accM;
        sBf[t] = accP;
        __syncthreads();
        if (t < 128) {
            atomicAdd(&pool[t],       sAf[t] + sAf[t + 128]);
            atomicAdd(&pool[128 + t], sBf[t] + sBf[t + 128]);
        }
    }
}

// ================= fallback path (b1 != 0), guarded, grid-capped =================

__global__ void k_scan_tileF(const int* __restrict__ in, int N,
                             int* __restrict__ out, int* __restrict__ tilesums,
                             const int* __restrict__ flags) {
    if (!flags[0]) return;
    __shared__ int sm[256];
    int t = threadIdx.x;
    int g = blockIdx.x * 256 + t;
    int v = (g < N) ? in[g] : 0;
    sm[t] = v;
    __syncthreads();
    for (int off = 1; off < 256; off <<= 1) {
        int x = sm[t];
        int y = (t >= off) ? sm[t - off] : 0;
        __syncthreads();
        sm[t] = x + y;
        __syncthreads();
    }
    int incl = sm[t];
    if (g < N) out[g] = incl - v;
    if (t == 255) tilesums[blockIdx.x] = incl;
}

__global__ void k_scan_sumsF(int* __restrict__ sums, int B, const int* __restrict__ flags) {
    if (!flags[0]) return;
    __shared__ int sm[1024];
    int t = threadIdx.x;
    int v = (t < B) ? sums[t] : 0;
    sm[t] = v;
    __syncthreads();
    for (int off = 1; off < 1024; off <<= 1) {
        int x = sm[t];
        int y = (t >= off) ? sm[t - off] : 0;
        __syncthreads();
        sm[t] = x + y;
        __syncthreads();
    }
    if (t < B) sums[t] = sm[t] - v;
}

__global__ void k_scan_addF(int* __restrict__ rowst, int Ntot,
                            const int* __restrict__ sums, int* __restrict__ cursor,
                            const int* __restrict__ flags) {
    if (!flags[0]) return;
    int g = blockIdx.x * 256 + threadIdx.x;
    if (g < Ntot) {
        int v = rowst[g] + sums[blockIdx.x];
        rowst[g] = v;
        cursor[g] = v;
    }
}

__global__ void k_build(const int* __restrict__ me, const int* __restrict__ pe,
                        int Em, int Ep, int Nm,
                        int* __restrict__ cursor, int* __restrict__ sorted,
                        const int* __restrict__ flags) {
    if (!flags[0]) return;
    int Etot = Em + Ep;
    for (int e = blockIdx.x * 256 + threadIdx.x; e < Etot; e += gridDim.x * 256) {
        int s, d;
        if (e < Em) { s = me[e];            d = me[Em + e]; }
        else        { int ee = e - Em; s = pe[ee] + Nm; d = pe[Ep + ee] + Nm; }
        int p = atomicAdd(&cursor[d], 1);
        sorted[p] = s;
    }
}

__global__ __launch_bounds__(256) void k_agg2(
        const int* __restrict__ rowst, const int* __restrict__ hist,
        const float2* __restrict__ si, const int* __restrict__ sorted,
        const float* __restrict__ W1, const float* __restrict__ b1,
        int Ntot, float* __restrict__ agg2, const int* __restrict__ flags) {
    if (!flags[0]) return;
    int lane = threadIdx.x & 63;
    int wv   = (blockIdx.x * 256 + threadIdx.x) >> 6;
    int nW   = gridDim.x * 4;
    float wa = W1[lane],  wb  = W1[lane + 64];
    float ba = b1[lane],  bbv = b1[lane + 64];
    for (int d = wv; d < Ntot; d += nW) {
        int st  = rowst[d];
        int cnt = hist[d];
        float aa = 0.f, ab = 0.f;
        for (int b0 = 0; b0 < cnt; b0 += 64) {
            int take = cnt - b0; if (take > 64) take = 64;
            int l = (lane < take) ? lane : 0;
            int idx = sorted[st + b0 + l];
            float2 sv = si[idx];
            for (int i = 0; i < take; ++i) {
                float s_i = __shfl(sv.x, i);
                float v_i = __shfl(sv.y, i);
                aa = fmaf(v_i, fmaxf(fmaf(s_i, wa, ba ), 0.f), aa);
                ab = fmaf(v_i, fmaxf(fmaf(s_i, wb, bbv), 0.f), ab);
            }
        }
        float2 ps = si[d];
        float oa = fmaxf(fmaf(ps.x, wa, ba ), 0.f);
        float ob = fmaxf(fmaf(ps.x, wb, bbv), 0.f);
        agg2[(size_t)d * 128 + lane]      = ps.y * (aa + ps.y * oa);
        agg2[(size_t)d * 128 + 64 + lane] = ps.y * (ab + ps.y * ob);
    }
}

__global__ __launch_bounds__(256, 2) void k_mm_pool(
        const float* __restrict__ agg2, const float* __restrict__ W2,
        const float* __restrict__ b2, int N, float* __restrict__ pool,
        const int* __restrict__ flags) {
    if (!flags[0]) return;
    __shared__ float sW[128 * 128];
    __shared__ float sR[8 * 128];
    int t = threadIdx.x;
    {
        const float4* srcp = (const float4*)W2;
        float4* dstp = (float4*)sW;
        for (int i = t; i < 128 * 128 / 4; i += 256) dstp[i] = srcp[i];
    }
    __syncthreads();

    int jg = t & 31;
    int rg = t >> 5;
    int j0 = jg * 4;
    const float4 bbv = *(const float4*)&b2[j0];
    float4 pA = make_float4(0.f, 0.f, 0.f, 0.f);

    for (int tile = blockIdx.x; tile * 64 < N; tile += gridDim.x) {
        int r0 = tile * 64 + rg * 8;
        const float* p0 = agg2 + (size_t)min(r0 + 0, N - 1) * 128;
        const float* p1 = agg2 + (size_t)min(r0 + 1, N - 1) * 128;
        const float* p2 = agg2 + (size_t)min(r0 + 2, N - 1) * 128;
        const float* p3 = agg2 + (size_t)min(r0 + 3, N - 1) * 128;
        const float* p4 = agg2 + (size_t)min(r0 + 4, N - 1) * 128;
        const float* p5 = agg2 + (size_t)min(r0 + 5, N - 1) * 128;
        const float* p6 = agg2 + (size_t)min(r0 + 6, N - 1) * 128;
        const float* p7 = agg2 + (size_t)min(r0 + 7, N - 1) * 128;

        float4 acc0 = bbv, acc1 = bbv, acc2 = bbv, acc3 = bbv;
        float4 acc4 = bbv, acc5 = bbv, acc6 = bbv, acc7 = bbv;
        float4 w0, w1, w2, w3;
        float4 xA0, xA1, xA2, xA3, xA4, xA5, xA6, xA7;
        float4 xB0, xB1, xB2, xB3, xB4, xB5, xB6, xB7;

#define LOADA(X, kk) \
        X##0 = *(const float4*)(p0 + (kk)); X##1 = *(const float4*)(p1 + (kk)); \
        X##2 = *(const float4*)(p2 + (kk)); X##3 = *(const float4*)(p3 + (kk)); \
        X##4 = *(const float4*)(p4 + (kk)); X##5 = *(const float4*)(p5 + (kk)); \
        X##6 = *(const float4*)(p6 + (kk)); X##7 = *(const float4*)(p7 + (kk));

#define WLOAD(kk) \
        w0 = *(const float4*)&sW[((kk) + 0) * 128 + j0]; \
        w1 = *(const float4*)&sW[((kk) + 1) * 128 + j0]; \
        w2 = *(const float4*)&sW[((kk) + 2) * 128 + j0]; \
        w3 = *(const float4*)&sW[((kk) + 3) * 128 + j0];

#define FMAROW(acc, av) \
        acc.x = fmaf(av.x, w0.x, acc.x); acc.y = fmaf(av.x, w0.y, acc.y); \
        acc.z = fmaf(av.x, w0.z, acc.z); acc.w = fmaf(av.x, w0.w, acc.w); \
        acc.x = fmaf(av.y, w1.x, acc.x); acc.y = fmaf(av.y, w1.y, acc.y); \
        acc.z = fmaf(av.y, w1.z, acc.z); acc.w = fmaf(av.y, w1.w, acc.w); \
        acc.x = fmaf(av.z, w2.x, acc.x); acc.y = fmaf(av.z, w2.y, acc.y); \
        acc.z = fmaf(av.z, w2.z, acc.z); acc.w = fmaf(av.z, w2.w, acc.w); \
        acc.x = fmaf(av.w, w3.x, acc.x); acc.y = fmaf(av.w, w3.y, acc.y); \
        acc.z = fmaf(av.w, w3.z, acc.z); acc.w = fmaf(av.w, w3.w, acc.w);

#define FMALL(X) \
        FMAROW(acc0, X##0) FMAROW(acc1, X##1) FMAROW(acc2, X##2) FMAROW(acc3, X##3) \
        FMAROW(acc4, X##4) FMAROW(acc5, X##5) FMAROW(acc6, X##6) FMAROW(acc7, X##7)

        LOADA(xA, 0)
        for (int k = 0; k < 128; k += 8) {
            LOADA(xB, k + 4)
            WLOAD(k)
            FMALL(xA)
            if (k + 8 < 128) { LOADA(xA, k + 8) }
            WLOAD(k + 4)
            FMALL(xB)
        }
#undef LOADA
#undef WLOAD
#undef FMAROW
#undef FMALL

#define POOLROW(i, acc) \
        if (r0 + i < N) { pA.x += fmaxf(acc.x, 0.f); pA.y += fmaxf(acc.y, 0.f); \
                          pA.z += fmaxf(acc.z, 0.f); pA.w += fmaxf(acc.w, 0.f); }
        POOLROW(0, acc0) POOLROW(1, acc1) POOLROW(2, acc2) POOLROW(3, acc3)
        POOLROW(4, acc4) POOLROW(5, acc5) POOLROW(6, acc6) POOLROW(7, acc7)
#undef POOLROW
    }

    *(float4*)&sR[rg * 128 + j0] = pA;
    __syncthreads();
    if (t < 128) {
        float s = 0.f;
        #pragma unroll
        for (int r = 0; r < 8; ++r) s += sR[r * 128 + t];
        atomicAdd(&pool[t], s);
    }
}

// ---------------- final 257-dim dot ----------------
__global__ void k_final(const float* __restrict__ pool, const float* __restrict__ phys,
                        const float* __restrict__ Wfc, const float* __restrict__ bfc,
                        float* __restrict__ out) {
    __shared__ float sm[256];
    int t = threadIdx.x;
    float acc = pool[t] * Wfc[t];
    if (t == 0) acc += phys[0] * Wfc[256] + bfc[0];
    sm[t] = acc;
    __syncthreads();
    for (int off = 128; off > 0; off >>= 1) {
        if (t < off) sm[t] += sm[t + off];
        __syncthreads();
    }
    if (t == 0) out[0] = sm[0];
}

extern "C" void kernel_launch(void* const* d_in, const int* in_sizes, int n_in,
                              void* d_out, int out_size, void* d_ws, size_t ws_size,
                              hipStream_t stream) {
    const float* mol_x  = (const float*)d_in[0];
    const int*   mol_e  = (const int*)  d_in[1];
    const float* prot_x = (const float*)d_in[2];
    const int*   prot_e = (const int*)  d_in[3];
    const float* phys   = (const float*)d_in[4];
    const float* W1     = (const float*)d_in[5];
    const float* b1     = (const float*)d_in[6];
    const float* W2     = (const float*)d_in[7];
    const float* b2     = (const float*)d_in[8];
    const float* Wfc    = (const float*)d_in[9];
    const float* bfc    = (const float*)d_in[10];
    float* out = (float*)d_out;

    int Nm = in_sizes[0], Em = in_sizes[1] / 2;
    int Np = in_sizes[2], Ep = in_sizes[3] / 2;
    int Ntot = Nm + Np, Etot = Em + Ep;

    char* p = (char*)d_ws;
    auto alloc = [&](size_t bytes) -> char* {
        char* r = p;
        p += (bytes + 255) & ~(size_t)255;
        return r;
    };
    float*  agg2  = (float*) alloc((size_t)Ntot * 128 * 4);   // fallback only
    int*    sorted= (int*)   alloc((size_t)Etot * 4);         // fallback only
    int*    pkb   = (int*)   alloc((size_t)Etot * 4);         // packed binned edges
    int*    hist  = (int*)   alloc((size_t)Ntot * 4);
    float*  s_acc = (float*) alloc((size_t)Ntot * 4);
    float*  PM    = (float*) alloc((size_t)Ntot * 8);
    float*  pool  = (float*) alloc(256 * 4);
    int*    btot  = (int*)   alloc(64 * 4);
    int*    gcur  = (int*)   alloc(64 * 4);
    int*    rowst = (int*)   alloc((size_t)Ntot * 4);         // fallback
    int*    cursor= (int*)   alloc((size_t)Ntot * 4);         // fallback
    int*    tilesB= (int*)   alloc(4096);                     // fallback
    float*  xi    = (float*) alloc((size_t)Ntot * 4);
    float2* si    = (float2*)alloc((size_t)Ntot * 8);
    float*  u     = (float*) alloc(128 * 4);
    float*  v     = (float*) alloc(128 * 4);
    int*    flags = (int*)   alloc(256);

    // ---- cooperative grid sizing (query, no allocation) ----
    int nbPerCU = 0;
    hipOccupancyMaxActiveBlocksPerMultiprocessor(&nbPerCU, k_mega, 256, 0);
    if (nbPerCU < 1) nbPerCU = 1;
    int dev = 0;
    hipGetDevice(&dev);
    hipDeviceProp_t prop;
    int numCU = (hipGetDeviceProperties(&prop, dev) == hipSuccess)
                    ? prop.multiProcessorCount : 256;
    int grid = numCU * nbPerCU;
    if (grid > 1024) grid = 1024;

    void* kargs[] = {
        (void*)&mol_x, (void*)&mol_e, (void*)&prot_x, (void*)&prot_e,
        (void*)&W1, (void*)&b1, (void*)&W2, (void*)&b2,
        (void*)&Nm, (void*)&Em, (void*)&Np, (void*)&Ep,
        (void*)&hist, (void*)&s_acc, (void*)&PM, (void*)&pool,
        (void*)&btot, (void*)&gcur, (void*)&pkb,
        (void*)&xi, (void*)&si, (void*)&u, (void*)&v, (void*)&flags
    };
    hipLaunchCooperativeKernel(k_mega, dim3(grid), dim3(256), kargs, 0, stream);

    // ---- fallback path (b1 != 0), guarded no-ops on fast path ----
    int B = CDIV(Ntot, 256);
    k_scan_tileF<<<B, 256, 0, stream>>>(hist, Ntot, rowst, tilesB, flags);
    k_scan_sumsF<<<1, 1024, 0, stream>>>(tilesB, B, flags);
    k_scan_addF <<<B, 256, 0, stream>>>(rowst, Ntot, tilesB, cursor, flags);
    k_build     <<<2048, 256, 0, stream>>>(mol_e, prot_e, Em, Ep, Nm,
                                           cursor, sorted, flags);
    k_agg2      <<<2048, 256, 0, stream>>>(rowst, hist, si, sorted, W1, b1, Ntot,
                                           agg2, flags);
    k_mm_pool   <<<512, 256, 0, stream>>>(agg2, W2, b2, Nm, pool, flags);
    k_mm_pool   <<<512, 256, 0, stream>>>(agg2 + (size_t)Nm * 128, W2, b2,
                                          Np, pool + 128, flags);

    k_final<<<1, 256, 0, stream>>>(pool, phys, Wfc, bfc, out);
}

// Round 11
// 341.289 us; speedup vs baseline: 2.9190x; 2.9190x over previous
//
#include <hip/hip_runtime.h>

#define CDIV(a,b) (((a)+(b)-1)/(b))
#define BINCAP 4096

// Combined node ids: mol [0,Nm), prot [Nm,Nm+Np).  Bucket = node >> 12 (4096 nodes/bkt,
// NBKT <= 64; node ids < 2^18 so (dlo<<18)|src packs an edge into one int).
// Dispatches: count(+flag,u,v) -> bin -> accA(deg, +xi via bucket ticket) ->
// accB(s_acc, +si via bucket ticket) -> accC(PM, fast only) -> pool_fact(+final via
// done ticket, fast only) -> fallback (single guarded kernel, b1!=0 only).
// Ticket rule: atomic flush -> __threadfence -> __syncthreads -> t0 ticket; last block
// re-reads accumulators with atomicAdd(p,0) (device-scope, dodges per-XCD L2 staleness).

// ---------------- count (+ flag + u/v in block 0) ----------------
__global__ __launch_bounds__(256) void k_count(
        const int* __restrict__ me, const int* __restrict__ pe,
        int Em, int Ep, int Nm, int per, int NBKT, int* __restrict__ btot,
        const float* __restrict__ b1, const float* __restrict__ W1,
        const float* __restrict__ W2, float* __restrict__ u, float* __restrict__ v,
        int* __restrict__ flags) {
    __shared__ int cnt[64];
    __shared__ int nz;
    int t = threadIdx.x, blk = blockIdx.x;
    int Etot = Em + Ep;
    int e0 = blk * per, e1 = min(e0 + per, Etot);
    if (t < 64) cnt[t] = 0;
    __syncthreads();
    for (int e = e0 + t; e < e1; e += 256) {
        int d = (e < Em) ? me[Em + e] : (pe[Ep + (e - Em)] + Nm);
        atomicAdd(&cnt[d >> 12], 1);
    }
    __syncthreads();
    if (t < NBKT && cnt[t]) atomicAdd(&btot[t], cnt[t]);
    if (blk == 0) {
        if (t == 0) nz = 0;
        __syncthreads();
        if (t < 128) {
            if (b1[t] != 0.f) atomicOr(&nz, 1);
            float au = 0.f, av = 0.f;
            for (int j = 0; j < 128; ++j) {
                float w = W1[j], w2 = W2[j * 128 + t];
                au = fmaf(fmaxf(w, 0.f), w2, au);
                av = fmaf(fmaxf(-w, 0.f), w2, av);
            }
            u[t] = au; v[t] = av;
        }
        __syncthreads();
        if (t == 0) flags[0] = nz;
    }
}

// ---------------- dynamic-reservation binning (packed writeout) ----------------
__global__ __launch_bounds__(256) void k_bin(
        const int* __restrict__ me, const int* __restrict__ pe,
        int Em, int Ep, int Nm, int per, int NBKT,
        const int* __restrict__ btot, int* __restrict__ gcur, int* __restrict__ pkb) {
    __shared__ int lpk[BINCAP];
    __shared__ unsigned char lbkt[BINCAP];
    __shared__ int cnt[64], cst[64], cur[64], wbase[64], bb[64];
    int t = threadIdx.x;
    int Etot = Em + Ep;
    int e0 = blockIdx.x * per, e1 = min(e0 + per, Etot);
    int ne = max(e1 - e0, 0);
    if (t < 64) cnt[t] = 0;
    __syncthreads();
    for (int e = e0 + t; e < e1; e += 256) {
        int d = (e < Em) ? me[Em + e] : (pe[Ep + (e - Em)] + Nm);
        atomicAdd(&cnt[d >> 12], 1);
    }
    __syncthreads();
    if (t == 0) {
        int run = 0, runb = 0;
        for (int b = 0; b < NBKT; ++b) {
            cst[b] = run; cur[b] = run; run += cnt[b];
            bb[b] = runb; runb += btot[b];
        }
    }
    __syncthreads();
    if (t < NBKT) wbase[t] = bb[t] + (cnt[t] ? atomicAdd(&gcur[t], cnt[t]) : 0);
    __syncthreads();
    for (int e = e0 + t; e < e1; e += 256) {
        int s, d;
        if (e < Em) { s = me[e];            d = me[Em + e]; }
        else        { int ee = e - Em; s = pe[ee] + Nm; d = pe[Ep + ee] + Nm; }
        int b = d >> 12;
        int p = atomicAdd(&cur[b], 1);
        lpk[p]  = ((d & 4095) << 18) | s;      // node ids < 2^18
        lbkt[p] = (unsigned char)b;
    }
    __syncthreads();
    for (int i = t; i < ne; i += 256) {
        int b = lbkt[i];
        pkb[wbase[b] + (i - cst[b])] = lpk[i];
    }
}

// ---------------- accA: degree histogram (+ xi tail via bucket ticket) ----------------
__global__ __launch_bounds__(256) void k_accA(
        const int* __restrict__ pkb, const int* __restrict__ btot,
        int NBKT, int WPB, int Ntot, int* __restrict__ hist, int* __restrict__ tickA,
        const float* __restrict__ mol_x, const float* __restrict__ prot_x,
        int Nm, float* __restrict__ xi) {
    __shared__ int h[4096];
    __shared__ int sbs, sbe, stk;
    int b = blockIdx.x / WPB, sl = blockIdx.x % WPB, t = threadIdx.x;
    if (t == 0) {
        int run = 0;
        for (int i = 0; i < b; ++i) run += btot[i];
        sbs = run; sbe = run + btot[b];
    }
    for (int k = t; k < 4096; k += 256) h[k] = 0;
    __syncthreads();
    for (int i = sbs + sl * 256 + t; i < sbe; i += WPB * 256)
        atomicAdd(&h[pkb[i] >> 18], 1);
    __syncthreads();
    int nbase = b << 12;
    for (int k = t; k < 4096; k += 256) {
        int vv = h[k];
        int node = nbase + k;
        if (vv && node < Ntot) atomicAdd(&hist[node], vv);
    }
    __threadfence();
    __syncthreads();
    if (t == 0) stk = atomicAdd(&tickA[b], 1);
    __syncthreads();
    if (stk == WPB - 1) {                        // last block of this bucket
        __threadfence();
        int nend = min(nbase + 4096, Ntot);
        for (int node = nbase + t; node < nend; node += 256) {
            int dg = atomicAdd(&hist[node], 0);  // coherent read
            float x = (node < Nm) ? mol_x[node] : prot_x[node - Nm];
            xi[node] = x * rsqrtf((float)(dg + 1));
        }
    }
}

// ---------------- accB: s_acc (+ si tail via bucket ticket) ----------------
__global__ __launch_bounds__(256) void k_accB(
        const int* __restrict__ pkb, const int* __restrict__ btot,
        const float* __restrict__ xi, int NBKT, int WPB, int Ntot,
        float* __restrict__ s_acc, int* __restrict__ tickB,
        const int* __restrict__ hist, float2* __restrict__ si) {
    __shared__ float acc[4096];
    __shared__ int sbs, sbe, stk;
    int b = blockIdx.x / WPB, sl = blockIdx.x % WPB, t = threadIdx.x;
    if (t == 0) {
        int run = 0;
        for (int i = 0; i < b; ++i) run += btot[i];
        sbs = run; sbe = run + btot[b];
    }
    for (int k = t; k < 4096; k += 256) acc[k] = 0.f;
    __syncthreads();
    for (int i = sbs + sl * 256 + t; i < sbe; i += WPB * 256) {
        int pk = pkb[i];
        atomicAdd(&acc[pk >> 18], xi[pk & 0x3FFFF]);
    }
    __syncthreads();
    int nbase = b << 12;
    for (int k = t; k < 4096; k += 256) {
        float vv = acc[k];
        int node = nbase + k;
        if (vv != 0.f && node < Ntot) atomicAdd(&s_acc[node], vv);
    }
    __threadfence();
    __syncthreads();
    if (t == 0) stk = atomicAdd(&tickB[b], 1);
    __syncthreads();
    if (stk == WPB - 1) {
        __threadfence();
        int nend = min(nbase + 4096, Ntot);
        for (int node = nbase + t; node < nend; node += 256) {
            float sa = atomicAdd(&s_acc[node], 0.f);          // coherent read
            float iv = rsqrtf((float)(hist[node] + 1));       // prev dispatch: safe
            si[node] = make_float2(iv * (sa + xi[node]), iv);
        }
    }
}

// ---------------- accC (fast only): P/M sign-split sums ----------------
__global__ __launch_bounds__(256) void k_accC(
        const int* __restrict__ pkb, const int* __restrict__ btot,
        const float2* __restrict__ si, int NBKT, int WPB, int Ntot,
        float* __restrict__ PM, const int* __restrict__ flags) {
    if (flags[0]) return;
    __shared__ float pm[8192];
    __shared__ int sbs, sbe;
    int b = blockIdx.x / WPB, sl = blockIdx.x % WPB, t = threadIdx.x;
    if (t == 0) {
        int run = 0;
        for (int i = 0; i < b; ++i) run += btot[i];
        sbs = run; sbe = run + btot[b];
    }
    for (int k = t; k < 8192; k += 256) pm[k] = 0.f;
    __syncthreads();
    for (int i = sbs + sl * 256 + t; i < sbe; i += WPB * 256) {
        int pk = pkb[i];
        float2 q = si[pk & 0x3FFFF];
        float val = q.y * q.x;
        int lo = (pk >> 18) * 2;
        if (val > 0.f)      atomicAdd(&pm[lo],     val);
        else if (val < 0.f) atomicAdd(&pm[lo + 1], -val);
    }
    __syncthreads();
    for (int k = t; k < 8192; k += 256) {
        float vv = pm[k];
        int node = (b << 12) + (k >> 1);
        if (vv != 0.f && node < Ntot) atomicAdd(&PM[2 * node + (k & 1)], vv);
    }
}

// ---------------- pool_fact (fast only): rank-2 pooled eval (+ final via done ticket) --
__global__ __launch_bounds__(256) void k_pool_fact(
        const float2* __restrict__ si, const float* __restrict__ PM,
        const float* __restrict__ u, const float* __restrict__ v,
        const float* __restrict__ b2, int Nm, int Np, int gm, int gp,
        float* __restrict__ pool,
        const float* __restrict__ phys, const float* __restrict__ Wfc,
        const float* __restrict__ bfc, float* __restrict__ out,
        int* __restrict__ done, const int* __restrict__ flags) {
    if (flags[0]) return;
    __shared__ float sA[2][128], sB[2][128], sR[2][128];
    __shared__ int sdone;
    int t = threadIdx.x;
    int k = t & 127;
    int grp = t >> 7;
    int blk = blockIdx.x;
    int Ntot = Nm + Np;
    int base, cnt, gstart, gsize;
    float* poolOut;
    if (blk < gm) { base = 0;  cnt = Nm; gstart = blk;      gsize = gm; poolOut = pool; }
    else          { base = Nm; cnt = Np; gstart = blk - gm; gsize = gp; poolOut = pool + 128; }
    float uk = u[k], vk = v[k], bk = b2[k];
    float acc = 0.f;
    int ntile = (cnt + 127) >> 7;
    for (int tb = gstart * 2; tb < ntile; tb += gsize * 2) {
        int tile = tb + grp;
        int d0 = base + tile * 128;
        int nn = (tile < ntile) ? min(128, base + cnt - d0) : 0;
        float A = 0.f, B = 0.f;
        if (k < nn) {
            float2 q  = si[d0 + k];                   // coalesced
            float2 pm = *(const float2*)&PM[2 * (d0 + k)];
            float iv = q.y;
            A = iv * fmaf(iv, fmaxf(q.x, 0.f), pm.x);
            B = iv * fmaf(iv, fmaxf(-q.x, 0.f), pm.y);
        }
        __syncthreads();
        sA[grp][k] = A;
        sB[grp][k] = B;
        __syncthreads();
        #pragma unroll 8
        for (int i = 0; i < nn; ++i)
            acc += fmaxf(fmaf(sA[grp][i], uk, fmaf(sB[grp][i], vk, bk)), 0.f);
    }
    __syncthreads();
    sR[grp][k] = acc;
    __syncthreads();
    if (t < 128) atomicAdd(&poolOut[t], sR[0][t] + sR[1][t]);
    // ---- done ticket: last block computes the 257-dim final dot ----
    __threadfence();
    __syncthreads();
    if (t == 0) sdone = atomicAdd(done, 1);
    __syncthreads();
    if (sdone == gm + gp - 1) {
        __threadfence();
        float* sf = &sR[0][0];                        // 256 floats scratch
        sf[t] = atomicAdd(&pool[t], 0.f) * Wfc[t];    // coherent read
        __syncthreads();
        for (int off = 128; off > 0; off >>= 1) {
            if (t < off) sf[t] += sf[t + off];
            __syncthreads();
        }
        if (t == 0) out[0] = sf[0] + phys[0] * Wfc[256] + bfc[0];
    }
    (void)Ntot;
}

// ---------------- fallback (b1 != 0): single-block, correctness-only ----------------
__global__ __launch_bounds__(1024) void k_fallback(
        const int* __restrict__ me, const int* __restrict__ pe,
        int Em, int Ep, int Nm, int Np,
        const int* __restrict__ hist, const float2* __restrict__ si,
        const float* __restrict__ W1, const float* __restrict__ b1,
        const float* __restrict__ W2, const float* __restrict__ b2,
        const float* __restrict__ phys, const float* __restrict__ Wfc,
        const float* __restrict__ bfc,
        int* __restrict__ rowst, int* __restrict__ cursor, int* __restrict__ sorted,
        float* __restrict__ pool, float* __restrict__ out,
        const int* __restrict__ flags) {
    if (!flags[0]) return;
    int t = threadIdx.x;
    int Ntot = Nm + Np, Etot = Em + Ep;
    __shared__ int ipart[1024];
    __shared__ float wrow[16][128];
    __shared__ float fred[256];
    // P1: exclusive scan of hist -> rowst, cursor
    int per = CDIV(Ntot, 1024);
    int a0 = min(t * per, Ntot), a1 = min(a0 + per, Ntot);
    int ssum = 0;
    for (int i = a0; i < a1; ++i) ssum += hist[i];
    ipart[t] = ssum;
    __syncthreads();
    if (t == 0) {
        int run = 0;
        for (int i = 0; i < 1024; ++i) { int vv = ipart[i]; ipart[i] = run; run += vv; }
    }
    __syncthreads();
    int run = ipart[t];
    for (int i = a0; i < a1; ++i) { rowst[i] = run; cursor[i] = run; run += hist[i]; }
    __threadfence();
    __syncthreads();
    // P2: CSR build
    for (int e = t; e < Etot; e += 1024) {
        int s, d;
        if (e < Em) { s = me[e];            d = me[Em + e]; }
        else        { int ee = e - Em; s = pe[ee] + Nm; d = pe[Ep + ee] + Nm; }
        int p = atomicAdd(&cursor[d], 1);
        sorted[p] = s;
    }
    __threadfence();
    __syncthreads();
    // P3: per-node layer2 agg + matmul + pool (one wave per node, 2 features/lane)
    int wid = t >> 6, lane = t & 63;
    float wa = W1[lane], wb = W1[lane + 64], ba = b1[lane], bb2 = b1[lane + 64];
    float pMa = 0.f, pMb = 0.f, pPa = 0.f, pPb = 0.f;
    for (int d = wid; d < Ntot; d += 16) {
        int st = rowst[d], en = st + hist[d];
        float aa = 0.f, ab = 0.f;
        for (int e = st; e < en; ++e) {
            float2 q = si[sorted[e]];
            aa = fmaf(q.y, fmaxf(fmaf(q.x, wa, ba ), 0.f), aa);
            ab = fmaf(q.y, fmaxf(fmaf(q.x, wb, bb2), 0.f), ab);
        }
        float2 ps = si[d];
        float oa = fmaxf(fmaf(ps.x, wa, ba ), 0.f);
        float ob = fmaxf(fmaf(ps.x, wb, bb2), 0.f);
        aa = ps.y * (aa + ps.y * oa);
        ab = ps.y * (ab + ps.y * ob);
        wrow[wid][lane]      = aa;       // wave-local LDS: ordered within the wave
        wrow[wid][lane + 64] = ab;
        float acc0 = b2[lane], acc1 = b2[lane + 64];
        for (int j = 0; j < 128; ++j) {
            float aj = wrow[wid][j];
            acc0 = fmaf(aj, W2[j * 128 + lane],      acc0);
            acc1 = fmaf(aj, W2[j * 128 + lane + 64], acc1);
        }
        float r0 = fmaxf(acc0, 0.f), r1 = fmaxf(acc1, 0.f);
        if (d < Nm) { pMa += r0; pMb += r1; } else { pPa += r0; pPb += r1; }
    }
    atomicAdd(&pool[lane],            pMa);
    atomicAdd(&pool[lane + 64],       pMb);
    atomicAdd(&pool[128 + lane],      pPa);
    atomicAdd(&pool[128 + lane + 64], pPb);
    __threadfence();
    __syncthreads();
    // P4: final dot
    if (t < 256) fred[t] = atomicAdd(&pool[t], 0.f) * Wfc[t];
    __syncthreads();
    for (int off = 128; off > 0; off >>= 1) {
        if (t < off) fred[t] += fred[t + off];
        __syncthreads();
    }
    if (t == 0) out[0] = fred[0] + phys[0] * Wfc[256] + bfc[0];
}

extern "C" void kernel_launch(void* const* d_in, const int* in_sizes, int n_in,
                              void* d_out, int out_size, void* d_ws, size_t ws_size,
                              hipStream_t stream) {
    const float* mol_x  = (const float*)d_in[0];
    const int*   mol_e  = (const int*)  d_in[1];
    const float* prot_x = (const float*)d_in[2];
    const int*   prot_e = (const int*)  d_in[3];
    const float* phys   = (const float*)d_in[4];
    const float* W1     = (const float*)d_in[5];
    const float* b1     = (const float*)d_in[6];
    const float* W2     = (const float*)d_in[7];
    const float* b2     = (const float*)d_in[8];
    const float* Wfc    = (const float*)d_in[9];
    const float* bfc    = (const float*)d_in[10];
    float* out = (float*)d_out;

    int Nm = in_sizes[0], Em = in_sizes[1] / 2;
    int Np = in_sizes[2], Ep = in_sizes[3] / 2;
    int Ntot = Nm + Np, Etot = Em + Ep;

    int NBKT = CDIV(Ntot, 4096);               // <= 64 (node ids < 2^18 for packing)
    int NBIN = CDIV(Etot, BINCAP);
    int per  = CDIV(Etot, NBIN);               // <= BINCAP

    char* p = (char*)d_ws;
    auto alloc = [&](size_t bytes) -> char* {
        char* r = p;
        p += (bytes + 255) & ~(size_t)255;
        return r;
    };
    int*    sorted= (int*)   alloc((size_t)Etot * 4);         // fallback only
    int*    pkb   = (int*)   alloc((size_t)Etot * 4);         // packed binned edges
    int*    hist  = (int*)   alloc((size_t)Ntot * 4);         // ---- memset region start
    float*  s_acc = (float*) alloc((size_t)Ntot * 4);
    float*  PM    = (float*) alloc((size_t)Ntot * 8);
    float*  pool  = (float*) alloc(256 * 4);
    int*    btot  = (int*)   alloc(64 * 4);
    int*    gcur  = (int*)   alloc(64 * 4);
    int*    tickA = (int*)   alloc(64 * 4);
    int*    tickB = (int*)   alloc(64 * 4);
    int*    done  = (int*)   alloc(64 * 4);                   // ---- memset region end
    int*    rowst = (int*)   alloc((size_t)Ntot * 4);         // fallback
    int*    cursor= (int*)   alloc((size_t)Ntot * 4);         // fallback
    float*  xi    = (float*) alloc((size_t)Ntot * 4);
    float2* si    = (float2*)alloc((size_t)Ntot * 8);
    float*  u     = (float*) alloc(128 * 4);
    float*  v     = (float*) alloc(128 * 4);
    int*    flags = (int*)   alloc(256);

    size_t zbytes = (char*)(done + 64) - (char*)hist;
    hipMemsetAsync(hist, 0, zbytes, stream);   // hist,s_acc,PM,pool,btot,gcur,ticks,done

    const int WPB_A = 32, WPB_B = 32, WPB_C = 16;

    k_count<<<NBIN, 256, 0, stream>>>(mol_e, prot_e, Em, Ep, Nm, per, NBKT, btot,
                                      b1, W1, W2, u, v, flags);
    k_bin  <<<NBIN, 256, 0, stream>>>(mol_e, prot_e, Em, Ep, Nm, per, NBKT,
                                      btot, gcur, pkb);
    k_accA <<<NBKT * WPB_A, 256, 0, stream>>>(pkb, btot, NBKT, WPB_A, Ntot, hist, tickA,
                                              mol_x, prot_x, Nm, xi);
    k_accB <<<NBKT * WPB_B, 256, 0, stream>>>(pkb, btot, xi, NBKT, WPB_B, Ntot,
                                              s_acc, tickB, hist, si);
    k_accC <<<NBKT * WPB_C, 256, 0, stream>>>(pkb, btot, si, NBKT, WPB_C, Ntot,
                                              PM, flags);
    {
        int gm = CDIV(CDIV(Nm, 128), 2);
        int gp = CDIV(CDIV(Np, 128), 2);
        k_pool_fact<<<gm + gp, 256, 0, stream>>>(si, PM, u, v, b2, Nm, Np, gm, gp,
                                                 pool, phys, Wfc, bfc, out, done, flags);
    }
    k_fallback<<<1, 1024, 0, stream>>>(mol_e, prot_e, Em, Ep, Nm, Np, hist, si,
                                       W1, b1, W2, b2, phys, Wfc, bfc,
                                       rowst, cursor, sorted, pool, out, flags);
}

// Round 12
// 159.385 us; speedup vs baseline: 6.2505x; 2.1413x over previous
//
#include <hip/hip_runtime.h>

#define CDIV(a,b) (((a)+(b)-1)/(b))
#define BINCAP 4096

// Combined node ids: mol [0,Nm), prot [Nm,Nm+Np).  Bucket = node >> 12 (4096 nodes/bkt,
// NBKT <= 64; node ids < 2^18 so (dlo<<18)|src packs an edge into one int).
// Dispatch-separated pipeline (dispatch boundary = cheapest global barrier on MI355X;
// grid.sync and per-block __threadfence tickets measured 2 orders worse, r10/r11):
// memset -> count(+flag,u,v) -> bin -> accA(deg) -> inv(xi) -> accB(s_acc) -> s(si)
// -> accC(PM, fast) -> pool_fact(fast) -> final -> fallback(b1!=0 only, single block).

// ---------------- count (+ flag + u/v in block 0) ----------------
__global__ __launch_bounds__(256) void k_count(
        const int* __restrict__ me, const int* __restrict__ pe,
        int Em, int Ep, int Nm, int per, int NBKT, int* __restrict__ btot,
        const float* __restrict__ b1, const float* __restrict__ W1,
        const float* __restrict__ W2, float* __restrict__ u, float* __restrict__ v,
        int* __restrict__ flags) {
    __shared__ int cnt[64];
    __shared__ int nz;
    int t = threadIdx.x, blk = blockIdx.x;
    int Etot = Em + Ep;
    int e0 = blk * per, e1 = min(e0 + per, Etot);
    if (t < 64) cnt[t] = 0;
    __syncthreads();
    for (int e = e0 + t; e < e1; e += 256) {
        int d = (e < Em) ? me[Em + e] : (pe[Ep + (e - Em)] + Nm);
        atomicAdd(&cnt[d >> 12], 1);
    }
    __syncthreads();
    if (t < NBKT && cnt[t]) atomicAdd(&btot[t], cnt[t]);
    if (blk == 0) {
        if (t == 0) nz = 0;
        __syncthreads();
        if (t < 128) {
            if (b1[t] != 0.f) atomicOr(&nz, 1);
            float au = 0.f, av = 0.f;
            for (int j = 0; j < 128; ++j) {
                float w = W1[j], w2 = W2[j * 128 + t];
                au = fmaf(fmaxf(w, 0.f), w2, au);
                av = fmaf(fmaxf(-w, 0.f), w2, av);
            }
            u[t] = au; v[t] = av;
        }
        __syncthreads();
        if (t == 0) flags[0] = nz;
    }
}

// ---------------- dynamic-reservation binning (packed writeout) ----------------
__global__ __launch_bounds__(256) void k_bin(
        const int* __restrict__ me, const int* __restrict__ pe,
        int Em, int Ep, int Nm, int per, int NBKT,
        const int* __restrict__ btot, int* __restrict__ gcur, int* __restrict__ pkb) {
    __shared__ int lpk[BINCAP];
    __shared__ unsigned char lbkt[BINCAP];
    __shared__ int cnt[64], cst[64], cur[64], wbase[64], bb[64];
    int t = threadIdx.x;
    int Etot = Em + Ep;
    int e0 = blockIdx.x * per, e1 = min(e0 + per, Etot);
    int ne = max(e1 - e0, 0);
    if (t < 64) cnt[t] = 0;
    __syncthreads();
    for (int e = e0 + t; e < e1; e += 256) {
        int d = (e < Em) ? me[Em + e] : (pe[Ep + (e - Em)] + Nm);
        atomicAdd(&cnt[d >> 12], 1);
    }
    __syncthreads();
    if (t == 0) {
        int run = 0, runb = 0;
        for (int b = 0; b < NBKT; ++b) {
            cst[b] = run; cur[b] = run; run += cnt[b];
            bb[b] = runb; runb += btot[b];
        }
    }
    __syncthreads();
    if (t < NBKT) wbase[t] = bb[t] + (cnt[t] ? atomicAdd(&gcur[t], cnt[t]) : 0);
    __syncthreads();
    for (int e = e0 + t; e < e1; e += 256) {
        int s, d;
        if (e < Em) { s = me[e];            d = me[Em + e]; }
        else        { int ee = e - Em; s = pe[ee] + Nm; d = pe[Ep + ee] + Nm; }
        int b = d >> 12;
        int p = atomicAdd(&cur[b], 1);
        lpk[p]  = ((d & 4095) << 18) | s;      // node ids < 2^18
        lbkt[p] = (unsigned char)b;
    }
    __syncthreads();
    for (int i = t; i < ne; i += 256) {
        int b = lbkt[i];
        pkb[wbase[b] + (i - cst[b])] = lpk[i];
    }
}

// ---------------- accA: degree histogram ----------------
__global__ __launch_bounds__(256) void k_accA(
        const int* __restrict__ pkb, const int* __restrict__ btot,
        int NBKT, int WPB, int Ntot, int* __restrict__ hist) {
    __shared__ int h[4096];
    __shared__ int sbs, sbe;
    int b = blockIdx.x / WPB, sl = blockIdx.x % WPB, t = threadIdx.x;
    if (t == 0) {
        int run = 0;
        for (int i = 0; i < b; ++i) run += btot[i];
        sbs = run; sbe = run + btot[b];
    }
    for (int k = t; k < 4096; k += 256) h[k] = 0;
    __syncthreads();
    for (int i = sbs + sl * 256 + t; i < sbe; i += WPB * 256)
        atomicAdd(&h[pkb[i] >> 18], 1);
    __syncthreads();
    for (int k = t; k < 4096; k += 256) {
        int vv = h[k];
        int node = (b << 12) + k;
        if (vv && node < Ntot) atomicAdd(&hist[node], vv);
    }
}

// ---------------- per-node: xi = x * rsqrt(deg+1) ----------------
__global__ void k_inv(const int* __restrict__ hist,
                      const float* __restrict__ mx, const float* __restrict__ px,
                      int Nm, int Ntot, float* __restrict__ xi) {
    int g = blockIdx.x * 256 + threadIdx.x;
    if (g < Ntot) {
        float x = (g < Nm) ? mx[g] : px[g - Nm];
        xi[g] = x * rsqrtf((float)(hist[g] + 1));
    }
}

// ---------------- accB: s_acc[d] += xi[src] ----------------
__global__ __launch_bounds__(256) void k_accB(
        const int* __restrict__ pkb, const int* __restrict__ btot,
        const float* __restrict__ xi, int NBKT, int WPB, int Ntot,
        float* __restrict__ s_acc) {
    __shared__ float acc[4096];
    __shared__ int sbs, sbe;
    int b = blockIdx.x / WPB, sl = blockIdx.x % WPB, t = threadIdx.x;
    if (t == 0) {
        int run = 0;
        for (int i = 0; i < b; ++i) run += btot[i];
        sbs = run; sbe = run + btot[b];
    }
    for (int k = t; k < 4096; k += 256) acc[k] = 0.f;
    __syncthreads();
    for (int i = sbs + sl * 256 + t; i < sbe; i += WPB * 256) {
        int pk = pkb[i];
        atomicAdd(&acc[pk >> 18], xi[pk & 0x3FFFF]);
    }
    __syncthreads();
    for (int k = t; k < 4096; k += 256) {
        float vv = acc[k];
        int node = (b << 12) + k;
        if (vv != 0.f && node < Ntot) atomicAdd(&s_acc[node], vv);
    }
}

// ---------------- s: si[d] = (inv*(s_acc+xi), inv) ----------------
__global__ void k_s(const int* __restrict__ hist, const float* __restrict__ s_acc,
                    const float* __restrict__ xi, int Ntot, float2* __restrict__ si) {
    int i = blockIdx.x * 256 + threadIdx.x;
    if (i >= Ntot) return;
    float iv = rsqrtf((float)(hist[i] + 1));
    si[i] = make_float2(iv * (s_acc[i] + xi[i]), iv);
}

// ---------------- accC (fast only): P/M sign-split sums ----------------
__global__ __launch_bounds__(256) void k_accC(
        const int* __restrict__ pkb, const int* __restrict__ btot,
        const float2* __restrict__ si, int NBKT, int WPB, int Ntot,
        float* __restrict__ PM, const int* __restrict__ flags) {
    if (flags[0]) return;
    __shared__ float pm[8192];
    __shared__ int sbs, sbe;
    int b = blockIdx.x / WPB, sl = blockIdx.x % WPB, t = threadIdx.x;
    if (t == 0) {
        int run = 0;
        for (int i = 0; i < b; ++i) run += btot[i];
        sbs = run; sbe = run + btot[b];
    }
    for (int k = t; k < 8192; k += 256) pm[k] = 0.f;
    __syncthreads();
    for (int i = sbs + sl * 256 + t; i < sbe; i += WPB * 256) {
        int pk = pkb[i];
        float2 q = si[pk & 0x3FFFF];
        float val = q.y * q.x;
        int lo = (pk >> 18) * 2;
        if (val > 0.f)      atomicAdd(&pm[lo],     val);
        else if (val < 0.f) atomicAdd(&pm[lo + 1], -val);
    }
    __syncthreads();
    for (int k = t; k < 8192; k += 256) {
        float vv = pm[k];
        int node = (b << 12) + (k >> 1);
        if (vv != 0.f && node < Ntot) atomicAdd(&PM[2 * node + (k & 1)], vv);
    }
}

// ---------------- pool_fact (fast only): rank-2 pooled eval, tile-transposed ----------
__global__ __launch_bounds__(256) void k_pool_fact(
        const float2* __restrict__ si, const float* __restrict__ PM,
        const float* __restrict__ u, const float* __restrict__ v,
        const float* __restrict__ b2, int Nm, int Np, int gm, int gp,
        float* __restrict__ pool, const int* __restrict__ flags) {
    if (flags[0]) return;
    __shared__ float sA[2][128], sB[2][128], sR[2][128];
    int t = threadIdx.x;
    int k = t & 127;
    int grp = t >> 7;
    int blk = blockIdx.x;
    int base, cnt, gstart, gsize;
    float* poolOut;
    if (blk < gm) { base = 0;  cnt = Nm; gstart = blk;      gsize = gm; poolOut = pool; }
    else          { base = Nm; cnt = Np; gstart = blk - gm; gsize = gp; poolOut = pool + 128; }
    float uk = u[k], vk = v[k], bk = b2[k];
    float acc = 0.f;
    int ntile = (cnt + 127) >> 7;
    for (int tb = gstart * 2; tb < ntile; tb += gsize * 2) {
        int tile = tb + grp;
        int d0 = base + tile * 128;
        int nn = (tile < ntile) ? min(128, base + cnt - d0) : 0;
        float A = 0.f, B = 0.f;
        if (k < nn) {
            float2 q  = si[d0 + k];                   // coalesced
            float2 pm = *(const float2*)&PM[2 * (d0 + k)];
            float iv = q.y;
            A = iv * fmaf(iv, fmaxf(q.x, 0.f), pm.x);
            B = iv * fmaf(iv, fmaxf(-q.x, 0.f), pm.y);
        }
        __syncthreads();
        sA[grp][k] = A;
        sB[grp][k] = B;
        __syncthreads();
        #pragma unroll 8
        for (int i = 0; i < nn; ++i)
            acc += fmaxf(fmaf(sA[grp][i], uk, fmaf(sB[grp][i], vk, bk)), 0.f);
    }
    __syncthreads();
    sR[grp][k] = acc;
    __syncthreads();
    if (t < 128) atomicAdd(&poolOut[t], sR[0][t] + sR[1][t]);
}

// ---------------- final 257-dim dot ----------------
__global__ void k_final(const float* __restrict__ pool, const float* __restrict__ phys,
                        const float* __restrict__ Wfc, const float* __restrict__ bfc,
                        float* __restrict__ out) {
    __shared__ float sm[256];
    int t = threadIdx.x;
    float acc = pool[t] * Wfc[t];
    if (t == 0) acc += phys[0] * Wfc[256] + bfc[0];
    sm[t] = acc;
    __syncthreads();
    for (int off = 128; off > 0; off >>= 1) {
        if (t < off) sm[t] += sm[t + off];
        __syncthreads();
    }
    if (t == 0) out[0] = sm[0];
}

// ---------------- fallback (b1 != 0): single-block, correctness-only ----------------
__global__ __launch_bounds__(1024) void k_fallback(
        const int* __restrict__ me, const int* __restrict__ pe,
        int Em, int Ep, int Nm, int Np,
        const int* __restrict__ hist, const float2* __restrict__ si,
        const float* __restrict__ W1, const float* __restrict__ b1,
        const float* __restrict__ W2, const float* __restrict__ b2,
        const float* __restrict__ phys, const float* __restrict__ Wfc,
        const float* __restrict__ bfc,
        int* __restrict__ rowst, int* __restrict__ cursor, int* __restrict__ sorted,
        float* __restrict__ pool, float* __restrict__ out,
        const int* __restrict__ flags) {
    if (!flags[0]) return;
    int t = threadIdx.x;
    int Ntot = Nm + Np, Etot = Em + Ep;
    __shared__ int ipart[1024];
    __shared__ float wrow[16][128];
    __shared__ float fred[256];
    // P1: exclusive scan of hist -> rowst, cursor
    int per = CDIV(Ntot, 1024);
    int a0 = min(t * per, Ntot), a1 = min(a0 + per, Ntot);
    int ssum = 0;
    for (int i = a0; i < a1; ++i) ssum += hist[i];
    ipart[t] = ssum;
    __syncthreads();
    if (t == 0) {
        int run = 0;
        for (int i = 0; i < 1024; ++i) { int vv = ipart[i]; ipart[i] = run; run += vv; }
    }
    __syncthreads();
    int run = ipart[t];
    for (int i = a0; i < a1; ++i) { rowst[i] = run; cursor[i] = run; run += hist[i]; }
    __threadfence();
    __syncthreads();
    // P2: CSR build
    for (int e = t; e < Etot; e += 1024) {
        int s, d;
        if (e < Em) { s = me[e];            d = me[Em + e]; }
        else        { int ee = e - Em; s = pe[ee] + Nm; d = pe[Ep + ee] + Nm; }
        int p = atomicAdd(&cursor[d], 1);
        sorted[p] = s;
    }
    __threadfence();
    __syncthreads();
    // P3: per-node layer2 agg + matmul + pool (one wave per node, 2 features/lane)
    int wid = t >> 6, lane = t & 63;
    float wa = W1[lane], wb = W1[lane + 64], ba = b1[lane], bb2 = b1[lane + 64];
    float pMa = 0.f, pMb = 0.f, pPa = 0.f, pPb = 0.f;
    for (int d = wid; d < Ntot; d += 16) {
        int st = rowst[d], en = st + hist[d];
        float aa = 0.f, ab = 0.f;
        for (int e = st; e < en; ++e) {
            float2 q = si[sorted[e]];
            aa = fmaf(q.y, fmaxf(fmaf(q.x, wa, ba ), 0.f), aa);
            ab = fmaf(q.y, fmaxf(fmaf(q.x, wb, bb2), 0.f), ab);
        }
        float2 ps = si[d];
        float oa = fmaxf(fmaf(ps.x, wa, ba ), 0.f);
        float ob = fmaxf(fmaf(ps.x, wb, bb2), 0.f);
        aa = ps.y * (aa + ps.y * oa);
        ab = ps.y * (ab + ps.y * ob);
        wrow[wid][lane]      = aa;       // wave-local LDS: ordered within the wave
        wrow[wid][lane + 64] = ab;
        float acc0 = b2[lane], acc1 = b2[lane + 64];
        for (int j = 0; j < 128; ++j) {
            float aj = wrow[wid][j];
            acc0 = fmaf(aj, W2[j * 128 + lane],      acc0);
            acc1 = fmaf(aj, W2[j * 128 + lane + 64], acc1);
        }
        float r0 = fmaxf(acc0, 0.f), r1 = fmaxf(acc1, 0.f);
        if (d < Nm) { pMa += r0; pMb += r1; } else { pPa += r0; pPb += r1; }
    }
    atomicAdd(&pool[lane],            pMa);
    atomicAdd(&pool[lane + 64],       pMb);
    atomicAdd(&pool[128 + lane],      pPa);
    atomicAdd(&pool[128 + lane + 64], pPb);
    __threadfence();
    __syncthreads();
    // P4: final dot (overwrites k_final's fast-path-only result)
    if (t < 256) fred[t] = atomicAdd(&pool[t], 0.f) * Wfc[t];
    __syncthreads();
    for (int off = 128; off > 0; off >>= 1) {
        if (t < off) fred[t] += fred[t + off];
        __syncthreads();
    }
    if (t == 0) out[0] = fred[0] + phys[0] * Wfc[256] + bfc[0];
}

extern "C" void kernel_launch(void* const* d_in, const int* in_sizes, int n_in,
                              void* d_out, int out_size, void* d_ws, size_t ws_size,
                              hipStream_t stream) {
    const float* mol_x  = (const float*)d_in[0];
    const int*   mol_e  = (const int*)  d_in[1];
    const float* prot_x = (const float*)d_in[2];
    const int*   prot_e = (const int*)  d_in[3];
    const float* phys   = (const float*)d_in[4];
    const float* W1     = (const float*)d_in[5];
    const float* b1     = (const float*)d_in[6];
    const float* W2     = (const float*)d_in[7];
    const float* b2     = (const float*)d_in[8];
    const float* Wfc    = (const float*)d_in[9];
    const float* bfc    = (const float*)d_in[10];
    float* out = (float*)d_out;

    int Nm = in_sizes[0], Em = in_sizes[1] / 2;
    int Np = in_sizes[2], Ep = in_sizes[3] / 2;
    int Ntot = Nm + Np, Etot = Em + Ep;

    int NBKT = CDIV(Ntot, 4096);               // <= 64 (node ids < 2^18 for packing)
    int NBIN = CDIV(Etot, BINCAP);
    int per  = CDIV(Etot, NBIN);               // <= BINCAP

    char* p = (char*)d_ws;
    auto alloc = [&](size_t bytes) -> char* {
        char* r = p;
        p += (bytes + 255) & ~(size_t)255;
        return r;
    };
    int*    sorted= (int*)   alloc((size_t)Etot * 4);         // fallback only
    int*    pkb   = (int*)   alloc((size_t)Etot * 4);         // packed binned edges
    int*    hist  = (int*)   alloc((size_t)Ntot * 4);         // ---- memset region start
    float*  s_acc = (float*) alloc((size_t)Ntot * 4);
    float*  PM    = (float*) alloc((size_t)Ntot * 8);
    float*  pool  = (float*) alloc(256 * 4);
    int*    btot  = (int*)   alloc(64 * 4);
    int*    gcur  = (int*)   alloc(64 * 4);                   // ---- memset region end
    int*    rowst = (int*)   alloc((size_t)Ntot * 4);         // fallback
    int*    cursor= (int*)   alloc((size_t)Ntot * 4);         // fallback
    float*  xi    = (float*) alloc((size_t)Ntot * 4);
    float2* si    = (float2*)alloc((size_t)Ntot * 8);
    float*  u     = (float*) alloc(128 * 4);
    float*  v     = (float*) alloc(128 * 4);
    int*    flags = (int*)   alloc(256);

    size_t zbytes = (char*)(gcur + 64) - (char*)hist;
    hipMemsetAsync(hist, 0, zbytes, stream);   // hist, s_acc, PM, pool, btot, gcur

    int B = CDIV(Ntot, 256);
    const int WPB_A = 32, WPB_B = 32, WPB_C = 16;

    k_count<<<NBIN, 256, 0, stream>>>(mol_e, prot_e, Em, Ep, Nm, per, NBKT, btot,
                                      b1, W1, W2, u, v, flags);
    k_bin  <<<NBIN, 256, 0, stream>>>(mol_e, prot_e, Em, Ep, Nm, per, NBKT,
                                      btot, gcur, pkb);
    k_accA <<<NBKT * WPB_A, 256, 0, stream>>>(pkb, btot, NBKT, WPB_A, Ntot, hist);
    k_inv  <<<B, 256, 0, stream>>>(hist, mol_x, prot_x, Nm, Ntot, xi);
    k_accB <<<NBKT * WPB_B, 256, 0, stream>>>(pkb, btot, xi, NBKT, WPB_B, Ntot, s_acc);
    k_s    <<<B, 256, 0, stream>>>(hist, s_acc, xi, Ntot, si);
    k_accC <<<NBKT * WPB_C, 256, 0, stream>>>(pkb, btot, si, NBKT, WPB_C, Ntot,
                                              PM, flags);
    {
        int gm = CDIV(CDIV(Nm, 128), 2);
        int gp = CDIV(CDIV(Np, 128), 2);
        k_pool_fact<<<gm + gp, 256, 0, stream>>>(si, PM, u, v, b2, Nm, Np, gm, gp,
                                                 pool, flags);
    }
    k_final<<<1, 256, 0, stream>>>(pool, phys, Wfc, bfc, out);
    k_fallback<<<1, 1024, 0, stream>>>(mol_e, prot_e, Em, Ep, Nm, Np, hist, si,
                                       W1, b1, W2, b2, phys, Wfc, bfc,
                                       rowst, cursor, sorted, pool, out, flags);
}

// Round 13
// 133.211 us; speedup vs baseline: 7.4786x; 1.1965x over previous
//
#include <hip/hip_runtime.h>

#define CDIV(a,b) (((a)+(b)-1)/(b))
#define CHUNK 4096

// Combined node ids: mol [0,Nm), prot [Nm,Nm+Np).  Bucket = node >> 12 (4096 nodes/bkt,
// NBKT <= 64; node ids < 2^18 so (dlo<<18)|src packs an edge into one int).
// Chunk-local binning: block c sorts its 4096-edge chunk in LDS by bucket, stores it to
// pkb[c*4096..] (coalesced, NO global atomics) + per-chunk directory cdir[c][b].
// acc kernels stream their bucket's slices via the directory into LDS-resident
// accumulators, then flush coalesced atomics.  Dispatch boundary = cheapest global
// barrier on MI355X (grid.sync / fence-tickets measured 2 orders worse, r10/r11).
// Pipeline: memset -> bin2(+flag,u,v) -> accA(deg) -> inv(xi) -> accB(s_acc) -> s(si)
// -> accC(PM, fast) -> pool_fact(fast) -> tail(final | fallback).
// Fast path (b1==0): relu bilinear sign-split -> rank-2 factorized layer 2.

// ---------------- bin: chunk-local LDS counting sort (+ flag/u/v in block 0) ----------
__global__ __launch_bounds__(256) void k_bin2(
        const int* __restrict__ me, const int* __restrict__ pe,
        int Em, int Ep, int Nm, int NBKT,
        int* __restrict__ pkb, int* __restrict__ cdir,
        const float* __restrict__ b1, const float* __restrict__ W1,
        const float* __restrict__ W2, float* __restrict__ u, float* __restrict__ v,
        int* __restrict__ flags) {
    __shared__ int lpk[CHUNK];
    __shared__ int cnt[64], cst[65], cur[64];
    __shared__ int nz;
    int t = threadIdx.x, c = blockIdx.x;
    int Etot = Em + Ep;
    int e0 = c * CHUNK, e1 = min(e0 + CHUNK, Etot);
    int ne = e1 - e0;
    if (t < 64) cnt[t] = 0;
    __syncthreads();
    for (int e = e0 + t; e < e1; e += 256) {
        int d = (e < Em) ? me[Em + e] : (pe[Ep + (e - Em)] + Nm);
        atomicAdd(&cnt[d >> 12], 1);
    }
    __syncthreads();
    if (t == 0) {
        int run = 0;
        for (int b = 0; b < NBKT; ++b) { cst[b] = run; cur[b] = run; run += cnt[b]; }
        cst[NBKT] = run;
    }
    __syncthreads();
    for (int e = e0 + t; e < e1; e += 256) {
        int s, d;
        if (e < Em) { s = me[e];            d = me[Em + e]; }
        else        { int ee = e - Em; s = pe[ee] + Nm; d = pe[Ep + ee] + Nm; }
        int b = d >> 12;
        int p = atomicAdd(&cur[b], 1);
        lpk[p] = ((d & 4095) << 18) | s;       // node ids < 2^18
    }
    __syncthreads();
    if (t <= NBKT) cdir[c * (NBKT + 1) + t] = cst[t];
    for (int i = t; i < ne; i += 256) pkb[e0 + i] = lpk[i];   // coalesced, no atomics
    if (c == 0) {
        if (t == 0) nz = 0;
        __syncthreads();
        if (t < 128) {
            if (b1[t] != 0.f) atomicOr(&nz, 1);
            float au = 0.f, av = 0.f;
            for (int j = 0; j < 128; ++j) {
                float w = W1[j], w2 = W2[j * 128 + t];
                au = fmaf(fmaxf(w, 0.f), w2, au);
                av = fmaf(fmaxf(-w, 0.f), w2, av);
            }
            u[t] = au; v[t] = av;
        }
        __syncthreads();
        if (t == 0) flags[0] = nz;
    }
}

// ---------------- accA: degree histogram (directory-sliced) ----------------
__global__ __launch_bounds__(256) void k_accA(
        const int* __restrict__ pkb, const int* __restrict__ cdir,
        int NBIN, int NBKT, int WPB, int Ntot, int* __restrict__ hist) {
    __shared__ int h[4096];
    int b = blockIdx.x / WPB, sl = blockIdx.x % WPB, t = threadIdx.x;
    for (int k = t; k < 4096; k += 256) h[k] = 0;
    __syncthreads();
    for (int c = sl; c < NBIN; c += WPB) {
        int base = c * (NBKT + 1);
        int s0 = cdir[base + b], s1 = cdir[base + b + 1];
        int p0 = c << 12;
        for (int i = s0 + t; i < s1; i += 256)
            atomicAdd(&h[pkb[p0 + i] >> 18], 1);
    }
    __syncthreads();
    int nb = b << 12;
    for (int k = t; k < 4096; k += 256) {
        int vv = h[k];
        int node = nb + k;
        if (vv && node < Ntot) atomicAdd(&hist[node], vv);
    }
}

// ---------------- per-node: xi = x * rsqrt(deg+1) ----------------
__global__ void k_inv(const int* __restrict__ hist,
                      const float* __restrict__ mx, const float* __restrict__ px,
                      int Nm, int Ntot, float* __restrict__ xi) {
    int g = blockIdx.x * 256 + threadIdx.x;
    if (g < Ntot) {
        float x = (g < Nm) ? mx[g] : px[g - Nm];
        xi[g] = x * rsqrtf((float)(hist[g] + 1));
    }
}

// ---------------- accB: s_acc[d] += xi[src] (directory-sliced) ----------------
__global__ __launch_bounds__(256) void k_accB(
        const int* __restrict__ pkb, const int* __restrict__ cdir,
        const float* __restrict__ xi, int NBIN, int NBKT, int WPB, int Ntot,
        float* __restrict__ s_acc) {
    __shared__ float acc[4096];
    int b = blockIdx.x / WPB, sl = blockIdx.x % WPB, t = threadIdx.x;
    for (int k = t; k < 4096; k += 256) acc[k] = 0.f;
    __syncthreads();
    for (int c = sl; c < NBIN; c += WPB) {
        int base = c * (NBKT + 1);
        int s0 = cdir[base + b], s1 = cdir[base + b + 1];
        int p0 = c << 12;
        for (int i = s0 + t; i < s1; i += 256) {
            int pk = pkb[p0 + i];
            atomicAdd(&acc[pk >> 18], xi[pk & 0x3FFFF]);
        }
    }
    __syncthreads();
    int nb = b << 12;
    for (int k = t; k < 4096; k += 256) {
        float vv = acc[k];
        int node = nb + k;
        if (vv != 0.f && node < Ntot) atomicAdd(&s_acc[node], vv);
    }
}

// ---------------- s: si[d] = (inv*(s_acc+xi), inv) ----------------
__global__ void k_s(const int* __restrict__ hist, const float* __restrict__ s_acc,
                    const float* __restrict__ xi, int Ntot, float2* __restrict__ si) {
    int i = blockIdx.x * 256 + threadIdx.x;
    if (i >= Ntot) return;
    float iv = rsqrtf((float)(hist[i] + 1));
    si[i] = make_float2(iv * (s_acc[i] + xi[i]), iv);
}

// ---------------- accC (fast only): P/M sign-split sums (directory-sliced) ------------
__global__ __launch_bounds__(256) void k_accC(
        const int* __restrict__ pkb, const int* __restrict__ cdir,
        const float2* __restrict__ si, int NBIN, int NBKT, int WPB, int Ntot,
        float* __restrict__ PM, const int* __restrict__ flags) {
    if (flags[0]) return;
    __shared__ float pm[8192];
    int b = blockIdx.x / WPB, sl = blockIdx.x % WPB, t = threadIdx.x;
    for (int k = t; k < 8192; k += 256) pm[k] = 0.f;
    __syncthreads();
    for (int c = sl; c < NBIN; c += WPB) {
        int base = c * (NBKT + 1);
        int s0 = cdir[base + b], s1 = cdir[base + b + 1];
        int p0 = c << 12;
        for (int i = s0 + t; i < s1; i += 256) {
            int pk = pkb[p0 + i];
            float2 q = si[pk & 0x3FFFF];
            float val = q.y * q.x;
            int lo = (pk >> 18) * 2;
            if (val > 0.f)      atomicAdd(&pm[lo],     val);
            else if (val < 0.f) atomicAdd(&pm[lo + 1], -val);
        }
    }
    __syncthreads();
    int nb = b << 12;
    for (int k = t; k < 8192; k += 256) {
        float vv = pm[k];
        int node = nb + (k >> 1);
        if (vv != 0.f && node < Ntot) atomicAdd(&PM[2 * node + (k & 1)], vv);
    }
}

// ---------------- pool_fact (fast only): rank-2 pooled eval, tile-transposed ----------
__global__ __launch_bounds__(256) void k_pool_fact(
        const float2* __restrict__ si, const float* __restrict__ PM,
        const float* __restrict__ u, const float* __restrict__ v,
        const float* __restrict__ b2, int Nm, int Np, int gm, int gp,
        float* __restrict__ pool, const int* __restrict__ flags) {
    if (flags[0]) return;
    __shared__ float sA[2][128], sB[2][128], sR[2][128];
    int t = threadIdx.x;
    int k = t & 127;
    int grp = t >> 7;
    int blk = blockIdx.x;
    int base, cnt, gstart, gsize;
    float* poolOut;
    if (blk < gm) { base = 0;  cnt = Nm; gstart = blk;      gsize = gm; poolOut = pool; }
    else          { base = Nm; cnt = Np; gstart = blk - gm; gsize = gp; poolOut = pool + 128; }
    float uk = u[k], vk = v[k], bk = b2[k];
    float acc = 0.f;
    int ntile = (cnt + 127) >> 7;
    for (int tb = gstart * 2; tb < ntile; tb += gsize * 2) {
        int tile = tb + grp;
        int d0 = base + tile * 128;
        int nn = (tile < ntile) ? min(128, base + cnt - d0) : 0;
        float A = 0.f, B = 0.f;
        if (k < nn) {
            float2 q  = si[d0 + k];                   // coalesced
            float2 pm = *(const float2*)&PM[2 * (d0 + k)];
            float iv = q.y;
            A = iv * fmaf(iv, fmaxf(q.x, 0.f), pm.x);
            B = iv * fmaf(iv, fmaxf(-q.x, 0.f), pm.y);
        }
        __syncthreads();
        sA[grp][k] = A;
        sB[grp][k] = B;
        __syncthreads();
        #pragma unroll 8
        for (int i = 0; i < nn; ++i)
            acc += fmaxf(fmaf(sA[grp][i], uk, fmaf(sB[grp][i], vk, bk)), 0.f);
    }
    __syncthreads();
    sR[grp][k] = acc;
    __syncthreads();
    if (t < 128) atomicAdd(&poolOut[t], sR[0][t] + sR[1][t]);
}

// ---------------- tail: final dot (fast) | full fallback (b1 != 0) ----------------
__global__ __launch_bounds__(1024) void k_tail(
        const int* __restrict__ me, const int* __restrict__ pe,
        int Em, int Ep, int Nm, int Np,
        const int* __restrict__ hist, const float2* __restrict__ si,
        const float* __restrict__ W1, const float* __restrict__ b1,
        const float* __restrict__ W2, const float* __restrict__ b2,
        const float* __restrict__ phys, const float* __restrict__ Wfc,
        const float* __restrict__ bfc,
        int* __restrict__ rowst, int* __restrict__ cursor, int* __restrict__ sorted,
        float* __restrict__ pool, float* __restrict__ out,
        const int* __restrict__ flags) {
    int t = threadIdx.x;
    if (flags[0] == 0) {
        // ---- fast path: final 257-dim dot ----
        __shared__ float sm[256];
        if (t < 256) {
            float acc = pool[t] * Wfc[t];
            if (t == 0) acc += phys[0] * Wfc[256] + bfc[0];
            sm[t] = acc;
        }
        __syncthreads();
        for (int off = 128; off > 0; off >>= 1) {
            if (t < off) sm[t] += sm[t + off];
            __syncthreads();
        }
        if (t == 0) out[0] = sm[0];
        return;
    }
    // ---- fallback (b1 != 0): single-block, correctness-only ----
    int Ntot = Nm + Np, Etot = Em + Ep;
    __shared__ int ipart[1024];
    __shared__ float wrow[16][128];
    __shared__ float fred[256];
    // P1: exclusive scan of hist -> rowst, cursor
    int per = CDIV(Ntot, 1024);
    int a0 = min(t * per, Ntot), a1 = min(a0 + per, Ntot);
    int ssum = 0;
    for (int i = a0; i < a1; ++i) ssum += hist[i];
    ipart[t] = ssum;
    __syncthreads();
    if (t == 0) {
        int run = 0;
        for (int i = 0; i < 1024; ++i) { int vv = ipart[i]; ipart[i] = run; run += vv; }
    }
    __syncthreads();
    int run = ipart[t];
    for (int i = a0; i < a1; ++i) { rowst[i] = run; cursor[i] = run; run += hist[i]; }
    __threadfence();
    __syncthreads();
    // P2: CSR build
    for (int e = t; e < Etot; e += 1024) {
        int s, d;
        if (e < Em) { s = me[e];            d = me[Em + e]; }
        else        { int ee = e - Em; s = pe[ee] + Nm; d = pe[Ep + ee] + Nm; }
        int p = atomicAdd(&cursor[d], 1);
        sorted[p] = s;
    }
    __threadfence();
    __syncthreads();
    // P3: per-node layer2 agg + matmul + pool (one wave per node, 2 features/lane)
    int wid = t >> 6, lane = t & 63;
    float wa = W1[lane], wb = W1[lane + 64], ba = b1[lane], bb2 = b1[lane + 64];
    float pMa = 0.f, pMb = 0.f, pPa = 0.f, pPb = 0.f;
    for (int d = wid; d < Ntot; d += 16) {
        int st = rowst[d], en = st + hist[d];
        float aa = 0.f, ab = 0.f;
        for (int e = st; e < en; ++e) {
            float2 q = si[sorted[e]];
            aa = fmaf(q.y, fmaxf(fmaf(q.x, wa, ba ), 0.f), aa);
            ab = fmaf(q.y, fmaxf(fmaf(q.x, wb, bb2), 0.f), ab);
        }
        float2 ps = si[d];
        float oa = fmaxf(fmaf(ps.x, wa, ba ), 0.f);
        float ob = fmaxf(fmaf(ps.x, wb, bb2), 0.f);
        aa = ps.y * (aa + ps.y * oa);
        ab = ps.y * (ab + ps.y * ob);
        wrow[wid][lane]      = aa;       // wave-local LDS: ordered within the wave
        wrow[wid][lane + 64] = ab;
        float acc0 = b2[lane], acc1 = b2[lane + 64];
        for (int j = 0; j < 128; ++j) {
            float aj = wrow[wid][j];
            acc0 = fmaf(aj, W2[j * 128 + lane],      acc0);
            acc1 = fmaf(aj, W2[j * 128 + lane + 64], acc1);
        }
        float r0 = fmaxf(acc0, 0.f), r1 = fmaxf(acc1, 0.f);
        if (d < Nm) { pMa += r0; pMb += r1; } else { pPa += r0; pPb += r1; }
    }
    atomicAdd(&pool[lane],            pMa);
    atomicAdd(&pool[lane + 64],       pMb);
    atomicAdd(&pool[128 + lane],      pPa);
    atomicAdd(&pool[128 + lane + 64], pPb);
    __threadfence();
    __syncthreads();
    // P4: final dot
    if (t < 256) fred[t] = atomicAdd(&pool[t], 0.f) * Wfc[t];
    __syncthreads();
    for (int off = 128; off > 0; off >>= 1) {
        if (t < off) fred[t] += fred[t + off];
        __syncthreads();
    }
    if (t == 0) out[0] = fred[0] + phys[0] * Wfc[256] + bfc[0];
}

extern "C" void kernel_launch(void* const* d_in, const int* in_sizes, int n_in,
                              void* d_out, int out_size, void* d_ws, size_t ws_size,
                              hipStream_t stream) {
    const float* mol_x  = (const float*)d_in[0];
    const int*   mol_e  = (const int*)  d_in[1];
    const float* prot_x = (const float*)d_in[2];
    const int*   prot_e = (const int*)  d_in[3];
    const float* phys   = (const float*)d_in[4];
    const float* W1     = (const float*)d_in[5];
    const float* b1     = (const float*)d_in[6];
    const float* W2     = (const float*)d_in[7];
    const float* b2     = (const float*)d_in[8];
    const float* Wfc    = (const float*)d_in[9];
    const float* bfc    = (const float*)d_in[10];
    float* out = (float*)d_out;

    int Nm = in_sizes[0], Em = in_sizes[1] / 2;
    int Np = in_sizes[2], Ep = in_sizes[3] / 2;
    int Ntot = Nm + Np, Etot = Em + Ep;

    int NBKT = CDIV(Ntot, 4096);               // <= 64 (node ids < 2^18 for packing)
    int NBIN = CDIV(Etot, CHUNK);              // chunk-local bins, fixed stride CHUNK

    char* p = (char*)d_ws;
    auto alloc = [&](size_t bytes) -> char* {
        char* r = p;
        p += (bytes + 255) & ~(size_t)255;
        return r;
    };
    int*    sorted= (int*)   alloc((size_t)Etot * 4);              // fallback only
    int*    pkb   = (int*)   alloc((size_t)NBIN * CHUNK * 4);      // chunk-local packed
    int*    cdir  = (int*)   alloc((size_t)NBIN * (NBKT + 1) * 4); // per-chunk directory
    int*    hist  = (int*)   alloc((size_t)Ntot * 4);              // -- memset start
    float*  s_acc = (float*) alloc((size_t)Ntot * 4);
    float*  PM    = (float*) alloc((size_t)Ntot * 8);
    float*  pool  = (float*) alloc(256 * 4);                       // -- memset end
    int*    rowst = (int*)   alloc((size_t)Ntot * 4);              // fallback
    int*    cursor= (int*)   alloc((size_t)Ntot * 4);              // fallback
    float*  xi    = (float*) alloc((size_t)Ntot * 4);
    float2* si    = (float2*)alloc((size_t)Ntot * 8);
    float*  u     = (float*) alloc(128 * 4);
    float*  v     = (float*) alloc(128 * 4);
    int*    flags = (int*)   alloc(256);

    size_t zbytes = (char*)(pool + 256) - (char*)hist;
    hipMemsetAsync(hist, 0, zbytes, stream);   // hist, s_acc, PM, pool

    int B = CDIV(Ntot, 256);
    const int WPB_A = 16, WPB_B = 32, WPB_C = 16;

    k_bin2<<<NBIN, 256, 0, stream>>>(mol_e, prot_e, Em, Ep, Nm, NBKT, pkb, cdir,
                                     b1, W1, W2, u, v, flags);
    k_accA<<<NBKT * WPB_A, 256, 0, stream>>>(pkb, cdir, NBIN, NBKT, WPB_A, Ntot, hist);
    k_inv <<<B, 256, 0, stream>>>(hist, mol_x, prot_x, Nm, Ntot, xi);
    k_accB<<<NBKT * WPB_B, 256, 0, stream>>>(pkb, cdir, xi, NBIN, NBKT, WPB_B, Ntot,
                                             s_acc);
    k_s   <<<B, 256, 0, stream>>>(hist, s_acc, xi, Ntot, si);
    k_accC<<<NBKT * WPB_C, 256, 0, stream>>>(pkb, cdir, si, NBIN, NBKT, WPB_C, Ntot,
                                             PM, flags);
    {
        int gm = CDIV(CDIV(Nm, 128), 2);
        int gp = CDIV(CDIV(Np, 128), 2);
        k_pool_fact<<<gm + gp, 256, 0, stream>>>(si, PM, u, v, b2, Nm, Np, gm, gp,
                                                 pool, flags);
    }
    k_tail<<<1, 1024, 0, stream>>>(mol_e, prot_e, Em, Ep, Nm, Np, hist, si,
                                   W1, b1, W2, b2, phys, Wfc, bfc,
                                   rowst, cursor, sorted, pool, out, flags);
}

// Round 14
// 127.831 us; speedup vs baseline: 7.7934x; 1.0421x over previous
//
#include <hip/hip_runtime.h>

#define CDIV(a,b) (((a)+(b)-1)/(b))
#define CHUNK 4096

// Combined node ids: mol [0,Nm), prot [Nm,Nm+Np).  Bucket = node >> 12 (4096 nodes/bkt,
// NBKT <= 64; node ids < 2^18 so (dlo<<18)|src packs an edge into one int).
// Chunk-local binning: block c sorts its 4096-edge chunk in LDS by bucket, stores it to
// pkb[c*4096..] (coalesced, NO global atomics) + per-chunk directory cdir[c][b].
// acc kernels stream their bucket's slices via the directory into LDS-resident
// accumulators, then flush coalesced atomics.  Dispatch boundary = cheapest global
// barrier on MI355X (grid.sync / fence-tickets measured 2 orders worse, r10/r11).
// Pipeline (7 dispatches): bin2(+zeroing,flag,u,v) -> accA(deg) -> accB(s_acc, xi on
// the fly) -> s(si) -> accC(PM, fast) -> pool_fact(fast) -> tail(final | fallback).
// Fast path (b1==0): relu bilinear sign-split -> rank-2 factorized layer 2.

// ---------------- bin: chunk-local LDS counting sort (+ zero-init, flag/u/v) ----------
__global__ __launch_bounds__(256) void k_bin2(
        const int* __restrict__ me, const int* __restrict__ pe,
        int Em, int Ep, int Nm, int Np, int NBKT,
        int* __restrict__ pkb, int* __restrict__ cdir,
        int* __restrict__ hist, float* __restrict__ s_acc,
        float* __restrict__ PM, float* __restrict__ pool,
        const float* __restrict__ b1, const float* __restrict__ W1,
        const float* __restrict__ W2, float* __restrict__ u, float* __restrict__ v,
        int* __restrict__ flags) {
    __shared__ int lpk[CHUNK];
    __shared__ int cnt[64], cst[65], cur[64];
    __shared__ int nz;
    int t = threadIdx.x, c = blockIdx.x;
    int Ntot = Nm + Np;
    int Etot = Em + Ep;
    // zero accumulators (consumed only by later dispatches)
    {
        int gtid = c * 256 + t, gstr = gridDim.x * 256;
        for (int i = gtid; i < Ntot; i += gstr) { hist[i] = 0; s_acc[i] = 0.f; }
        for (int i = gtid; i < 2 * Ntot; i += gstr) PM[i] = 0.f;
        if (gtid < 256) pool[gtid] = 0.f;
    }
    int e0 = c * CHUNK, e1 = min(e0 + CHUNK, Etot);
    int ne = e1 - e0;
    if (t < 64) cnt[t] = 0;
    __syncthreads();
    for (int e = e0 + t; e < e1; e += 256) {
        int d = (e < Em) ? me[Em + e] : (pe[Ep + (e - Em)] + Nm);
        atomicAdd(&cnt[d >> 12], 1);
    }
    __syncthreads();
    if (t == 0) {
        int run = 0;
        for (int b = 0; b < NBKT; ++b) { cst[b] = run; cur[b] = run; run += cnt[b]; }
        cst[NBKT] = run;
    }
    __syncthreads();
    for (int e = e0 + t; e < e1; e += 256) {
        int s, d;
        if (e < Em) { s = me[e];            d = me[Em + e]; }
        else        { int ee = e - Em; s = pe[ee] + Nm; d = pe[Ep + ee] + Nm; }
        int b = d >> 12;
        int p = atomicAdd(&cur[b], 1);
        lpk[p] = ((d & 4095) << 18) | s;       // node ids < 2^18
    }
    __syncthreads();
    if (t <= NBKT) cdir[c * (NBKT + 1) + t] = cst[t];
    for (int i = t; i < ne; i += 256) pkb[e0 + i] = lpk[i];   // coalesced, no atomics
    if (c == 0) {
        if (t == 0) nz = 0;
        __syncthreads();
        if (t < 128) {
            if (b1[t] != 0.f) atomicOr(&nz, 1);
            float au = 0.f, av = 0.f;
            for (int j = 0; j < 128; ++j) {
                float w = W1[j], w2 = W2[j * 128 + t];
                au = fmaf(fmaxf(w, 0.f), w2, au);
                av = fmaf(fmaxf(-w, 0.f), w2, av);
            }
            u[t] = au; v[t] = av;
        }
        __syncthreads();
        if (t == 0) flags[0] = nz;
    }
}

// ---------------- accA: degree histogram (directory-sliced) ----------------
__global__ __launch_bounds__(256) void k_accA(
        const int* __restrict__ pkb, const int* __restrict__ cdir,
        int NBIN, int NBKT, int WPB, int Ntot, int* __restrict__ hist) {
    __shared__ int h[4096];
    int b = blockIdx.x / WPB, sl = blockIdx.x % WPB, t = threadIdx.x;
    for (int k = t; k < 4096; k += 256) h[k] = 0;
    __syncthreads();
    for (int c = sl; c < NBIN; c += WPB) {
        int base = c * (NBKT + 1);
        int s0 = cdir[base + b], s1 = cdir[base + b + 1];
        int p0 = c << 12;
        for (int i = s0 + t; i < s1; i += 256)
            atomicAdd(&h[pkb[p0 + i] >> 18], 1);
    }
    __syncthreads();
    int nb = b << 12;
    for (int k = t; k < 4096; k += 256) {
        int vv = h[k];
        int node = nb + k;
        if (vv && node < Ntot) atomicAdd(&hist[node], vv);
    }
}

// ---------------- accB: s_acc[d] += x[src]*rsqrt(deg[src]+1)  (xi on the fly) ---------
__global__ __launch_bounds__(256) void k_accB(
        const int* __restrict__ pkb, const int* __restrict__ cdir,
        const int* __restrict__ hist, const float* __restrict__ mol_x,
        const float* __restrict__ prot_x, int Nm,
        int NBIN, int NBKT, int WPB, int Ntot, float* __restrict__ s_acc) {
    __shared__ float acc[4096];
    int b = blockIdx.x / WPB, sl = blockIdx.x % WPB, t = threadIdx.x;
    for (int k = t; k < 4096; k += 256) acc[k] = 0.f;
    __syncthreads();
    for (int c = sl; c < NBIN; c += WPB) {
        int base = c * (NBKT + 1);
        int s0 = cdir[base + b], s1 = cdir[base + b + 1];
        int p0 = c << 12;
        for (int i = s0 + t; i < s1; i += 256) {
            int pk = pkb[p0 + i];
            int s = pk & 0x3FFFF;
            float x = (s < Nm) ? mol_x[s] : prot_x[s - Nm];
            atomicAdd(&acc[pk >> 18], x * rsqrtf((float)(hist[s] + 1)));
        }
    }
    __syncthreads();
    int nb = b << 12;
    for (int k = t; k < 4096; k += 256) {
        float vv = acc[k];
        int node = nb + k;
        if (vv != 0.f && node < Ntot) atomicAdd(&s_acc[node], vv);
    }
}

// ---------------- s: si[d] = (inv*(s_acc + x*inv), inv) ----------------
__global__ void k_s(const int* __restrict__ hist, const float* __restrict__ s_acc,
                    const float* __restrict__ mol_x, const float* __restrict__ prot_x,
                    int Nm, int Ntot, float2* __restrict__ si) {
    int i = blockIdx.x * 256 + threadIdx.x;
    if (i >= Ntot) return;
    float x = (i < Nm) ? mol_x[i] : prot_x[i - Nm];
    float iv = rsqrtf((float)(hist[i] + 1));
    si[i] = make_float2(iv * (s_acc[i] + x * iv), iv);
}

// ---------------- accC (fast only): P/M sign-split sums (directory-sliced) ------------
__global__ __launch_bounds__(256) void k_accC(
        const int* __restrict__ pkb, const int* __restrict__ cdir,
        const float2* __restrict__ si, int NBIN, int NBKT, int WPB, int Ntot,
        float* __restrict__ PM, const int* __restrict__ flags) {
    if (flags[0]) return;
    __shared__ float pm[8192];
    int b = blockIdx.x / WPB, sl = blockIdx.x % WPB, t = threadIdx.x;
    for (int k = t; k < 8192; k += 256) pm[k] = 0.f;
    __syncthreads();
    for (int c = sl; c < NBIN; c += WPB) {
        int base = c * (NBKT + 1);
        int s0 = cdir[base + b], s1 = cdir[base + b + 1];
        int p0 = c << 12;
        for (int i = s0 + t; i < s1; i += 256) {
            int pk = pkb[p0 + i];
            float2 q = si[pk & 0x3FFFF];
            float val = q.y * q.x;
            int lo = (pk >> 18) * 2;
            if (val > 0.f)      atomicAdd(&pm[lo],     val);
            else if (val < 0.f) atomicAdd(&pm[lo + 1], -val);
        }
    }
    __syncthreads();
    int nb = b << 12;
    for (int k = t; k < 8192; k += 256) {
        float vv = pm[k];
        int node = nb + (k >> 1);
        if (vv != 0.f && node < Ntot) atomicAdd(&PM[2 * node + (k & 1)], vv);
    }
}

// ---------------- pool_fact (fast only): rank-2 pooled eval, tile-transposed ----------
__global__ __launch_bounds__(256) void k_pool_fact(
        const float2* __restrict__ si, const float* __restrict__ PM,
        const float* __restrict__ u, const float* __restrict__ v,
        const float* __restrict__ b2, int Nm, int Np, int gm, int gp,
        float* __restrict__ pool, const int* __restrict__ flags) {
    if (flags[0]) return;
    __shared__ float sA[2][128], sB[2][128], sR[2][128];
    int t = threadIdx.x;
    int k = t & 127;
    int grp = t >> 7;
    int blk = blockIdx.x;
    int base, cnt, gstart, gsize;
    float* poolOut;
    if (blk < gm) { base = 0;  cnt = Nm; gstart = blk;      gsize = gm; poolOut = pool; }
    else          { base = Nm; cnt = Np; gstart = blk - gm; gsize = gp; poolOut = pool + 128; }
    float uk = u[k], vk = v[k], bk = b2[k];
    float acc = 0.f;
    int ntile = (cnt + 127) >> 7;
    for (int tb = gstart * 2; tb < ntile; tb += gsize * 2) {
        int tile = tb + grp;
        int d0 = base + tile * 128;
        int nn = (tile < ntile) ? min(128, base + cnt - d0) : 0;
        float A = 0.f, B = 0.f;
        if (k < nn) {
            float2 q  = si[d0 + k];                   // coalesced
            float2 pm = *(const float2*)&PM[2 * (d0 + k)];
            float iv = q.y;
            A = iv * fmaf(iv, fmaxf(q.x, 0.f), pm.x);
            B = iv * fmaf(iv, fmaxf(-q.x, 0.f), pm.y);
        }
        __syncthreads();
        sA[grp][k] = A;
        sB[grp][k] = B;
        __syncthreads();
        #pragma unroll 8
        for (int i = 0; i < nn; ++i)
            acc += fmaxf(fmaf(sA[grp][i], uk, fmaf(sB[grp][i], vk, bk)), 0.f);
    }
    __syncthreads();
    sR[grp][k] = acc;
    __syncthreads();
    if (t < 128) atomicAdd(&poolOut[t], sR[0][t] + sR[1][t]);
}

// ---------------- tail: final dot (fast) | full fallback (b1 != 0) ----------------
__global__ __launch_bounds__(1024) void k_tail(
        const int* __restrict__ me, const int* __restrict__ pe,
        int Em, int Ep, int Nm, int Np,
        const int* __restrict__ hist, const float2* __restrict__ si,
        const float* __restrict__ W1, const float* __restrict__ b1,
        const float* __restrict__ W2, const float* __restrict__ b2,
        const float* __restrict__ phys, const float* __restrict__ Wfc,
        const float* __restrict__ bfc,
        int* __restrict__ rowst, int* __restrict__ cursor, int* __restrict__ sorted,
        float* __restrict__ pool, float* __restrict__ out,
        const int* __restrict__ flags) {
    int t = threadIdx.x;
    if (flags[0] == 0) {
        // ---- fast path: final 257-dim dot ----
        __shared__ float sm[256];
        if (t < 256) {
            float acc = pool[t] * Wfc[t];
            if (t == 0) acc += phys[0] * Wfc[256] + bfc[0];
            sm[t] = acc;
        }
        __syncthreads();
        for (int off = 128; off > 0; off >>= 1) {
            if (t < off) sm[t] += sm[t + off];
            __syncthreads();
        }
        if (t == 0) out[0] = sm[0];
        return;
    }
    // ---- fallback (b1 != 0): single-block, correctness-only ----
    int Ntot = Nm + Np, Etot = Em + Ep;
    __shared__ int ipart[1024];
    __shared__ float wrow[16][128];
    __shared__ float fred[256];
    // P1: exclusive scan of hist -> rowst, cursor
    int per = CDIV(Ntot, 1024);
    int a0 = min(t * per, Ntot), a1 = min(a0 + per, Ntot);
    int ssum = 0;
    for (int i = a0; i < a1; ++i) ssum += hist[i];
    ipart[t] = ssum;
    __syncthreads();
    if (t == 0) {
        int run = 0;
        for (int i = 0; i < 1024; ++i) { int vv = ipart[i]; ipart[i] = run; run += vv; }
    }
    __syncthreads();
    int run = ipart[t];
    for (int i = a0; i < a1; ++i) { rowst[i] = run; cursor[i] = run; run += hist[i]; }
    __threadfence();
    __syncthreads();
    // P2: CSR build
    for (int e = t; e < Etot; e += 1024) {
        int s, d;
        if (e < Em) { s = me[e];            d = me[Em + e]; }
        else        { int ee = e - Em; s = pe[ee] + Nm; d = pe[Ep + ee] + Nm; }
        int p = atomicAdd(&cursor[d], 1);
        sorted[p] = s;
    }
    __threadfence();
    __syncthreads();
    // P3: per-node layer2 agg + matmul + pool (one wave per node, 2 features/lane)
    int wid = t >> 6, lane = t & 63;
    float wa = W1[lane], wb = W1[lane + 64], ba = b1[lane], bb2 = b1[lane + 64];
    float pMa = 0.f, pMb = 0.f, pPa = 0.f, pPb = 0.f;
    for (int d = wid; d < Ntot; d += 16) {
        int st = rowst[d], en = st + hist[d];
        float aa = 0.f, ab = 0.f;
        for (int e = st; e < en; ++e) {
            float2 q = si[sorted[e]];
            aa = fmaf(q.y, fmaxf(fmaf(q.x, wa, ba ), 0.f), aa);
            ab = fmaf(q.y, fmaxf(fmaf(q.x, wb, bb2), 0.f), ab);
        }
        float2 ps = si[d];
        float oa = fmaxf(fmaf(ps.x, wa, ba ), 0.f);
        float ob = fmaxf(fmaf(ps.x, wb, bb2), 0.f);
        aa = ps.y * (aa + ps.y * oa);
        ab = ps.y * (ab + ps.y * ob);
        wrow[wid][lane]      = aa;       // wave-local LDS: ordered within the wave
        wrow[wid][lane + 64] = ab;
        float acc0 = b2[lane], acc1 = b2[lane + 64];
        for (int j = 0; j < 128; ++j) {
            float aj = wrow[wid][j];
            acc0 = fmaf(aj, W2[j * 128 + lane],      acc0);
            acc1 = fmaf(aj, W2[j * 128 + lane + 64], acc1);
        }
        float r0 = fmaxf(acc0, 0.f), r1 = fmaxf(acc1, 0.f);
        if (d < Nm) { pMa += r0; pMb += r1; } else { pPa += r0; pPb += r1; }
    }
    atomicAdd(&pool[lane],            pMa);
    atomicAdd(&pool[lane + 64],       pMb);
    atomicAdd(&pool[128 + lane],      pPa);
    atomicAdd(&pool[128 + lane + 64], pPb);
    __threadfence();
    __syncthreads();
    // P4: final dot
    if (t < 256) fred[t] = atomicAdd(&pool[t], 0.f) * Wfc[t];
    __syncthreads();
    for (int off = 128; off > 0; off >>= 1) {
        if (t < off) fred[t] += fred[t + off];
        __syncthreads();
    }
    if (t == 0) out[0] = fred[0] + phys[0] * Wfc[256] + bfc[0];
}

extern "C" void kernel_launch(void* const* d_in, const int* in_sizes, int n_in,
                              void* d_out, int out_size, void* d_ws, size_t ws_size,
                              hipStream_t stream) {
    const float* mol_x  = (const float*)d_in[0];
    const int*   mol_e  = (const int*)  d_in[1];
    const float* prot_x = (const float*)d_in[2];
    const int*   prot_e = (const int*)  d_in[3];
    const float* phys   = (const float*)d_in[4];
    const float* W1     = (const float*)d_in[5];
    const float* b1     = (const float*)d_in[6];
    const float* W2     = (const float*)d_in[7];
    const float* b2     = (const float*)d_in[8];
    const float* Wfc    = (const float*)d_in[9];
    const float* bfc    = (const float*)d_in[10];
    float* out = (float*)d_out;

    int Nm = in_sizes[0], Em = in_sizes[1] / 2;
    int Np = in_sizes[2], Ep = in_sizes[3] / 2;
    int Ntot = Nm + Np, Etot = Em + Ep;

    int NBKT = CDIV(Ntot, 4096);               // <= 64 (node ids < 2^18 for packing)
    int NBIN = CDIV(Etot, CHUNK);              // chunk-local bins, fixed stride CHUNK

    char* p = (char*)d_ws;
    auto alloc = [&](size_t bytes) -> char* {
        char* r = p;
        p += (bytes + 255) & ~(size_t)255;
        return r;
    };
    int*    sorted= (int*)   alloc((size_t)Etot * 4);              // fallback only
    int*    pkb   = (int*)   alloc((size_t)NBIN * CHUNK * 4);      // chunk-local packed
    int*    cdir  = (int*)   alloc((size_t)NBIN * (NBKT + 1) * 4); // per-chunk directory
    int*    hist  = (int*)   alloc((size_t)Ntot * 4);
    float*  s_acc = (float*) alloc((size_t)Ntot * 4);
    float*  PM    = (float*) alloc((size_t)Ntot * 8);
    float*  pool  = (float*) alloc(256 * 4);
    int*    rowst = (int*)   alloc((size_t)Ntot * 4);              // fallback
    int*    cursor= (int*)   alloc((size_t)Ntot * 4);              // fallback
    float2* si    = (float2*)alloc((size_t)Ntot * 8);
    float*  u     = (float*) alloc(128 * 4);
    float*  v     = (float*) alloc(128 * 4);
    int*    flags = (int*)   alloc(256);

    int B = CDIV(Ntot, 256);
    const int WPB_A = 16, WPB_B = 16, WPB_C = 16;

    k_bin2<<<NBIN, 256, 0, stream>>>(mol_e, prot_e, Em, Ep, Nm, Np, NBKT, pkb, cdir,
                                     hist, s_acc, PM, pool, b1, W1, W2, u, v, flags);
    k_accA<<<NBKT * WPB_A, 256, 0, stream>>>(pkb, cdir, NBIN, NBKT, WPB_A, Ntot, hist);
    k_accB<<<NBKT * WPB_B, 256, 0, stream>>>(pkb, cdir, hist, mol_x, prot_x, Nm,
                                             NBIN, NBKT, WPB_B, Ntot, s_acc);
    k_s   <<<B, 256, 0, stream>>>(hist, s_acc, mol_x, prot_x, Nm, Ntot, si);
    k_accC<<<NBKT * WPB_C, 256, 0, stream>>>(pkb, cdir, si, NBIN, NBKT, WPB_C, Ntot,
                                             PM, flags);
    {
        int gm = CDIV(CDIV(Nm, 128), 2);
        int gp = CDIV(CDIV(Np, 128), 2);
        k_pool_fact<<<gm + gp, 256, 0, stream>>>(si, PM, u, v, b2, Nm, Np, gm, gp,
                                                 pool, flags);
    }
    k_tail<<<1, 1024, 0, stream>>>(mol_e, prot_e, Em, Ep, Nm, Np, hist, si,
                                   W1, b1, W2, b2, phys, Wfc, bfc,
                                   rowst, cursor, sorted, pool, out, flags);
}